// Round 6
// baseline (267.171 us; speedup 1.0000x reference)
//
#include <hip/hip_runtime.h>
#include <stdint.h>

#define B_ 2
#define T_ 2048
#define DM 2048
#define NH 16
#define NKV 8
#define HD 128
#define NQKV 4096
#define SC2_ 0.12753102765f  // (1/sqrt(128)) * log2(e)

typedef float fx4 __attribute__((ext_vector_type(4)));
typedef float fx16 __attribute__((ext_vector_type(16)));
typedef __bf16 bfx8 __attribute__((ext_vector_type(8)));
typedef unsigned int ux4 __attribute__((ext_vector_type(4)));
typedef unsigned short u16;
typedef unsigned int u32;

typedef __attribute__((address_space(1))) const void gas_t;
typedef __attribute__((address_space(3))) void las_t;

__device__ __forceinline__ u16 f2bf(float f) {
  u32 u = __float_as_uint(f);
  u = (u + 0x7fffu + ((u >> 16) & 1u)) >> 16;
  return (u16)u;
}
__device__ __forceinline__ u32 pk2bf(float lo, float hi) {
  return (u32)f2bf(lo) | ((u32)f2bf(hi) << 16);
}

// async global->LDS, 16B per lane; lds arg must be wave-uniform base + lane*16
__device__ __forceinline__ void stage16(const void* g, void* l) {
  __builtin_amdgcn_global_load_lds((gas_t*)(uintptr_t)g, (las_t*)(uintptr_t)l,
                                   16, 0, 0);
}

// ---------------- fp32 -> bf16 convert ----------------
__global__ void k_cvt(const float* __restrict__ in, u16* __restrict__ out, int n) {
  int i = (blockIdx.x * blockDim.x + threadIdx.x) * 4;
  if (i + 3 < n) {
    float4 v = *(const float4*)(in + i);
    u32 w0 = (u32)f2bf(v.x) | ((u32)f2bf(v.y) << 16);
    u32 w1 = (u32)f2bf(v.z) | ((u32)f2bf(v.w) << 16);
    *(uint2*)(out + i) = make_uint2(w0, w1);
  }
}

// ======== 256x256 8-phase GEMM (T2+T3+T4+T5): C[M][N] = A[M][K] B[N][K]^T ========
__global__ __launch_bounds__(512, 2) void k_gemm256(const u16* __restrict__ A,
                                                    const u16* __restrict__ Bm,
                                                    u16* __restrict__ C,
                                                    int M, int N, int K) {
  __shared__ __align__(16) u16 As[2][2][256 * 32];
  __shared__ __align__(16) u16 Bs[2][2][256 * 32];
  const int nbn = N >> 8;
  const int bm = blockIdx.x / nbn, bn = blockIdx.x % nbn;
  const int tid = threadIdx.x;
  const int w = tid >> 6, lane = tid & 63;
  const int wm = w >> 2, wn = w & 3;
  const int lr = lane & 15, lg = lane >> 4;
  const int cw = (lg ^ ((lr >> 1) & 3)) * 8;
  const u16* Ab = A + (size_t)bm * 256 * K;
  const u16* Bb = Bm + (size_t)bn * 256 * K;
  const int NT = K >> 6;

  auto stage = [&](const u16* gb, u16* region, int tile, int kh) {
#pragma unroll
    for (int i = 0; i < 2; i++) {
      int q = tid + i * 512;
      int row = q >> 2, ch = q & 3;
      int sc = ch ^ ((row >> 1) & 3);
      stage16(gb + (size_t)row * K + tile * 64 + kh * 32 + sc * 8, region + q * 8);
    }
  };

  fx4 acc[8][4];
  const fx4 zero4 = {0.f, 0.f, 0.f, 0.f};
#pragma unroll
  for (int m = 0; m < 8; m++)
#pragma unroll
    for (int n = 0; n < 4; n++) acc[m][n] = zero4;

  stage(Ab, &As[0][0][0], 0, 0);
  stage(Bb, &Bs[0][0][0], 0, 0);
  stage(Ab, &As[0][1][0], 0, 1);
  stage(Bb, &Bs[0][1][0], 0, 1);
  stage(Ab, &As[1][0][0], 1, 0);
  stage(Bb, &Bs[1][0][0], 1, 0);
  asm volatile("s_waitcnt vmcnt(4)" ::: "memory");
  __builtin_amdgcn_s_barrier();

  const int arow = (wm * 128 + lr) * 32;
  const int brow = (wn * 64 + lr) * 32;
  bfx8 af[4], bf[4];

#pragma unroll 1
  for (int t = 0; t < NT; t++) {
    const u16* A0 = &As[t & 1][0][0];
    const u16* A1 = &As[t & 1][1][0];
    const u16* B0 = &Bs[t & 1][0][0];
    const u16* B1 = &Bs[t & 1][1][0];
    const int p1 = (t + 1) & 1, p2 = t & 1;

#pragma unroll
    for (int mi = 0; mi < 4; mi++) af[mi] = *(const bfx8*)(A0 + arow + mi * 512 + cw);
#pragma unroll
    for (int n = 0; n < 4; n++) bf[n] = *(const bfx8*)(B0 + brow + n * 512 + cw);
    if (t + 1 < NT) stage(Ab, &As[p1][1][0], t + 1, 1);
    __builtin_amdgcn_s_barrier();
    asm volatile("s_waitcnt lgkmcnt(0)" ::: "memory");
    __builtin_amdgcn_sched_barrier(0);
    __builtin_amdgcn_s_setprio(1);
#pragma unroll
    for (int mi = 0; mi < 4; mi++)
#pragma unroll
      for (int n = 0; n < 4; n++)
        acc[mi][n] = __builtin_amdgcn_mfma_f32_16x16x32_bf16(af[mi], bf[n], acc[mi][n], 0, 0, 0);
    __builtin_amdgcn_s_setprio(0);
    __builtin_amdgcn_s_barrier();

#pragma unroll
    for (int mi = 0; mi < 4; mi++)
      af[mi] = *(const bfx8*)(A0 + arow + 2048 + mi * 512 + cw);
    if (t + 1 < NT) stage(Bb, &Bs[p1][1][0], t + 1, 1);
    __builtin_amdgcn_s_barrier();
    asm volatile("s_waitcnt lgkmcnt(0)" ::: "memory");
    __builtin_amdgcn_sched_barrier(0);
    __builtin_amdgcn_s_setprio(1);
#pragma unroll
    for (int mi = 0; mi < 4; mi++)
#pragma unroll
      for (int n = 0; n < 4; n++)
        acc[4 + mi][n] = __builtin_amdgcn_mfma_f32_16x16x32_bf16(af[mi], bf[n], acc[4 + mi][n], 0, 0, 0);
    __builtin_amdgcn_s_setprio(0);
    __builtin_amdgcn_s_barrier();

#pragma unroll
    for (int mi = 0; mi < 4; mi++) af[mi] = *(const bfx8*)(A1 + arow + mi * 512 + cw);
#pragma unroll
    for (int n = 0; n < 4; n++) bf[n] = *(const bfx8*)(B1 + brow + n * 512 + cw);
    if (t + 2 < NT) stage(Ab, &As[p2][0][0], t + 2, 0);
    __builtin_amdgcn_s_barrier();
    asm volatile("s_waitcnt lgkmcnt(0)" ::: "memory");
    __builtin_amdgcn_sched_barrier(0);
    __builtin_amdgcn_s_setprio(1);
#pragma unroll
    for (int mi = 0; mi < 4; mi++)
#pragma unroll
      for (int n = 0; n < 4; n++)
        acc[mi][n] = __builtin_amdgcn_mfma_f32_16x16x32_bf16(af[mi], bf[n], acc[mi][n], 0, 0, 0);
    __builtin_amdgcn_s_setprio(0);
    __builtin_amdgcn_s_barrier();

#pragma unroll
    for (int mi = 0; mi < 4; mi++)
      af[mi] = *(const bfx8*)(A1 + arow + 2048 + mi * 512 + cw);
    if (t + 2 < NT) stage(Bb, &Bs[p2][0][0], t + 2, 0);
    __builtin_amdgcn_s_barrier();
    asm volatile("s_waitcnt lgkmcnt(0)" ::: "memory");
    __builtin_amdgcn_sched_barrier(0);
    __builtin_amdgcn_s_setprio(1);
#pragma unroll
    for (int mi = 0; mi < 4; mi++)
#pragma unroll
      for (int n = 0; n < 4; n++)
        acc[4 + mi][n] = __builtin_amdgcn_mfma_f32_16x16x32_bf16(af[mi], bf[n], acc[4 + mi][n], 0, 0, 0);
    __builtin_amdgcn_s_setprio(0);
    asm volatile("s_waitcnt vmcnt(4)" ::: "memory");
    __builtin_amdgcn_s_barrier();
  }

  const int r0 = bm * 256 + wm * 128, c0 = bn * 256 + wn * 64;
#pragma unroll
  for (int m = 0; m < 8; m++) {
#pragma unroll
    for (int n = 0; n < 4; n++) {
      int c = c0 + n * 16 + lr;
#pragma unroll
      for (int i = 0; i < 4; i++)
        C[(size_t)(r0 + m * 16 + lg * 4 + i) * N + c] = f2bf(acc[m][n][i]);
    }
  }
}

// ---------------- bf16 GEMM (128^2 m97-structure), used for out-proj ----------------
template <bool OUT_F32>
__global__ __launch_bounds__(256, 2) void k_gemm(const u16* __restrict__ A,
                                                 const u16* __restrict__ Bm,
                                                 void* __restrict__ Cv,
                                                 const float* __restrict__ bias,
                                                 int M, int N, int K) {
  __shared__ __align__(16) u16 As[128 * 32];
  __shared__ __align__(16) u16 Bs[128 * 32];
  const int nbn = N >> 7;
  const int bm = blockIdx.x / nbn, bn = blockIdx.x % nbn;
  const int tid = threadIdx.x;
  const int w = tid >> 6, lane = tid & 63;
  const int wr = w >> 1, wc = w & 1;
  const int lr = lane & 15, lg = lane >> 4;
  const u16* Ab = A + (size_t)bm * 128 * K;
  const u16* Bb = Bm + (size_t)bn * 128 * K;
  const int srow = lane >> 2, skc = (lane & 3) * 8;

  fx4 zero4 = {0.f, 0.f, 0.f, 0.f};
  fx4 acc[4][4];
#pragma unroll
  for (int m = 0; m < 4; m++)
#pragma unroll
    for (int n = 0; n < 4; n++) acc[m][n] = zero4;

  for (int k0 = 0; k0 < K; k0 += 32) {
#pragma unroll
    for (int t = 0; t < 2; t++) {
      int s = w + t * 4;
      stage16(Ab + (size_t)(s * 16 + srow) * K + k0 + skc, As + s * 512 + lane * 8);
      stage16(Bb + (size_t)(s * 16 + srow) * K + k0 + skc, Bs + s * 512 + lane * 8);
    }
    __syncthreads();
    bfx8 af[4], bfr[4];
#pragma unroll
    for (int m = 0; m < 4; m++)
      af[m] = *(const bfx8*)(As + (wr * 64 + m * 16 + lr) * 32 + lg * 8);
#pragma unroll
    for (int n = 0; n < 4; n++)
      bfr[n] = *(const bfx8*)(Bs + (wc * 64 + n * 16 + lr) * 32 + lg * 8);
#pragma unroll
    for (int m = 0; m < 4; m++)
#pragma unroll
      for (int n = 0; n < 4; n++)
        acc[m][n] = __builtin_amdgcn_mfma_f32_16x16x32_bf16(af[m], bfr[n], acc[m][n], 0, 0, 0);
    __syncthreads();
  }

  const int r0 = bm * 128 + wr * 64, c0 = bn * 128 + wc * 64;
#pragma unroll
  for (int m = 0; m < 4; m++) {
#pragma unroll
    for (int n = 0; n < 4; n++) {
      int c = c0 + n * 16 + lr;
#pragma unroll
      for (int i = 0; i < 4; i++) {
        int r = r0 + m * 16 + lg * 4 + i;
        if (OUT_F32) {
          ((float*)Cv)[(size_t)r * N + c] = acc[m][n][i] + bias[c];
        } else {
          ((u16*)Cv)[(size_t)r * N + c] = f2bf(acc[m][n][i]);
        }
      }
    }
  }
}

// ---------------- Q/K epilogue: rmsnorm + rope, relayout ----------------
__global__ __launch_bounds__(256) void k_qkpost(const u16* __restrict__ qkv,
                                                const float* __restrict__ cosp,
                                                const float* __restrict__ sinp,
                                                const float* __restrict__ gq,
                                                const float* __restrict__ gk,
                                                u16* __restrict__ Qo,
                                                u16* __restrict__ Ko) {
  int bi = blockIdx.x;
  int hh = bi % 24;
  int t64 = (bi / 24) % 32;
  int b = bi / 768;
  int tid = threadIdx.x;
  int j = tid >> 2, p = tid & 3;
  int t = t64 * 64 + j;
  bool isq = hh < 16;
  int colbase = isq ? hh * 128 : 2048 + (hh - 16) * 128;
  const u16* src = qkv + ((size_t)(b * T_ + t)) * NQKV + colbase + p * 32;

  float xv[32];
#pragma unroll
  for (int c = 0; c < 4; c++) {
    uint4 raw = *(const uint4*)(src + c * 8);
    u32 wd[4] = {raw.x, raw.y, raw.z, raw.w};
#pragma unroll
    for (int q2 = 0; q2 < 4; q2++) {
      xv[c * 8 + q2 * 2 + 0] = __uint_as_float(wd[q2] << 16);
      xv[c * 8 + q2 * 2 + 1] = __uint_as_float(wd[q2] & 0xffff0000u);
    }
  }
  float ss = 0.f;
#pragma unroll
  for (int i = 0; i < 32; i++) ss += xv[i] * xv[i];
  ss += __shfl_xor(ss, 1);
  ss += __shfl_xor(ss, 2);
  float rinv = rsqrtf(ss * (1.0f / 128.0f) + 1e-6f);
  const float* g = isq ? gq : gk;
  const float* cr = cosp + (size_t)t * 128 + p * 32;
  const float* sr = sinp + (size_t)t * 128 + p * 32;

  float ov[32];
#pragma unroll
  for (int i = 0; i < 32; i++) {
    float y = xv[i] * rinv * g[p * 32 + i];
    float oth = __shfl_xor(y, 2);
    float rot = (p < 2) ? -oth : oth;
    ov[i] = y * cr[i] + rot * sr[i];
  }

  uint4 pk[4];
#pragma unroll
  for (int c = 0; c < 4; c++) {
    u32 wd[4];
#pragma unroll
    for (int q2 = 0; q2 < 4; q2++)
      wd[q2] = (u32)f2bf(ov[c * 8 + q2 * 2]) | ((u32)f2bf(ov[c * 8 + q2 * 2 + 1]) << 16);
    pk[c] = make_uint4(wd[0], wd[1], wd[2], wd[3]);
  }

  if (isq) {
    u16* dst = Qo + (((size_t)(b * NH + hh)) * T_ + t) * HD + p * 32;
#pragma unroll
    for (int c = 0; c < 4; c++) *(uint4*)(dst + c * 8) = pk[c];
  } else {
    int hk = hh - 16;
    u16* dstrow = Ko + (((size_t)(b * NKV + hk)) * T_ + t) * HD;
#pragma unroll
    for (int c = 0; c < 4; c++) {
      int C = p * 4 + c;
      int Cs = C ^ (t & 7);  // XOR swizzle (16 chunks/row), matches attn read
      *(uint4*)(dstrow + Cs * 8) = pk[c];
    }
  }
}

// ---------------- V transpose: qkv[...,3072+] -> vt[b][hkv][d][t] ----------------
__global__ __launch_bounds__(256) void k_vtr(const u16* __restrict__ qkv,
                                             u16* __restrict__ vt) {
  __shared__ __align__(16) u16 sm[128 * 64];
  int bi = blockIdx.x;
  int hv = bi & 7;
  int t64 = (bi >> 3) & 31;
  int b = bi >> 8;
  int tid = threadIdx.x;
#pragma unroll
  for (int it = 0; it < 4; it++) {
    int idx = tid + it * 256;
    int tok = idx >> 4, c = idx & 15;
    uint4 raw = *(const uint4*)(qkv + ((size_t)(b * T_ + t64 * 64 + tok)) * NQKV +
                                3072 + hv * 128 + c * 8);
    u32 wd[4] = {raw.x, raw.y, raw.z, raw.w};
#pragma unroll
    for (int q2 = 0; q2 < 4; q2++) {
      sm[(c * 8 + q2 * 2 + 0) * 64 + tok] = (u16)(wd[q2] & 0xffffu);
      sm[(c * 8 + q2 * 2 + 1) * 64 + tok] = (u16)(wd[q2] >> 16);
    }
  }
  __syncthreads();
  int d = tid >> 1, half = tid & 1;
  size_t rowb = (((size_t)(b * NKV + hv)) * HD + d) * T_ + t64 * 64;
#pragma unroll
  for (int c = 0; c < 4; c++) {
    int cg = half * 4 + c;
    int cs = cg ^ (d & 7);
    u32 wd[4];
#pragma unroll
    for (int q2 = 0; q2 < 4; q2++) {
      u32 lo = sm[d * 64 + half * 32 + c * 8 + 2 * q2];
      u32 hi = sm[d * 64 + half * 32 + c * 8 + 2 * q2 + 1];
      wd[q2] = lo | (hi << 16);
    }
    *(uint4*)(vt + rowb + cs * 8) = make_uint4(wd[0], wd[1], wd[2], wd[3]);
  }
}

// ---------------- flash attention v3 (causal, GQA rep=2) ----------------
// grid = B*NH*16 = 512 blocks, 256 thr (4 waves). Each wave owns 32 q-rows:
// two waves on tile z, two on tile 31-z (shared KV stream, prefix property).
// 32x32x16 MFMA, swapped QK^T (S^T), in-register P via pk+permlane32_swap
// (no P LDS), O^T via mfma(V^T, P^T) so l-norm is lane-local. No-max softmax
// (rmsnorm-bounded scores). Raw barriers + counted vmcnt.
__global__ __launch_bounds__(256, 2) void k_attn(const u16* __restrict__ Qg,
                                                 const u16* __restrict__ Kg,
                                                 const u16* __restrict__ Vg,
                                                 u16* __restrict__ Og) {
  __shared__ __align__(16) u16 Ks[2][64 * 128];
  __shared__ __align__(16) u16 Vs[2][128 * 64];
  const int bi = blockIdx.x;
  const int zr = bi & 15, h = (bi >> 4) & 15, b = bi >> 8;
  const int z = b ? (15 - zr) : zr;  // heavy+light pairing across grid halves
  const int hkv = h >> 1;
  const int tid = threadIdx.x, w = tid >> 6, lane = tid & 63;
  const int q31 = lane & 31, H8 = lane >> 5;
  const int sel = ((w >> 1) ^ bi) & 1;      // flip per block: balance SIMDs
  const int zt = sel ? (31 - z) : z;        // this wave's q-tile
  const int qr0 = zt * 64 + (w & 1) * 32;   // wave's 32-row base
  const int qg = qr0 + q31;                 // lane's q row (global in T)
  const int nch = 32 - z;
  const int myl = zt + 1;

  const u16* kb = Kg + ((size_t)(b * NKV + hkv)) * T_ * HD;
  const u16* vb = Vg + ((size_t)(b * NKV + hkv)) * HD * T_;

  // Q regs: B-frag per 16-d step: lane holds Q[qg][d = step*16 + 8*H8 + j]
  const u16* qrow = Qg + (((size_t)(b * NH + h)) * T_ + qg) * HD;
  bfx8 qf[8];
#pragma unroll
  for (int step = 0; step < 8; step++)
    qf[step] = *(const bfx8*)(qrow + step * 16 + H8 * 8);

  fx16 o[4];
  const fx16 zero16 = {0.f, 0.f, 0.f, 0.f, 0.f, 0.f, 0.f, 0.f,
                       0.f, 0.f, 0.f, 0.f, 0.f, 0.f, 0.f, 0.f};
#pragma unroll
  for (int db = 0; db < 4; db++) o[db] = zero16;
  float l_i = 0.f;

  // 256 threads stage K[64][128] + V[128][64] (32KB): 8 x 16B per thread.
  auto stageKV = [&](int buf, int kv0) {
    u16* Kd = &Ks[buf][0];
    u16* Vd = &Vs[buf][0];
#pragma unroll
    for (int it = 0; it < 4; it++) {
      int r = it * 16 + (tid >> 4);
      stage16(kb + (size_t)(kv0 + r) * HD + (tid & 15) * 8, Kd + it * 2048 + tid * 8);
      int d = it * 32 + (tid >> 3);
      stage16(vb + (size_t)d * T_ + kv0 + (tid & 7) * 8, Vd + it * 2048 + tid * 8);
    }
  };

  stageKV(0, 0);
  asm volatile("s_waitcnt vmcnt(0)" ::: "memory");
  __builtin_amdgcn_s_barrier();
  int cur = 0;

#pragma unroll 1
  for (int ch = 0; ch < nch; ch++) {
    if (ch + 1 < nch) {
      stageKV(cur ^ 1, (ch + 1) * 64);
      asm volatile("s_waitcnt vmcnt(8)" ::: "memory");
    } else {
      asm volatile("s_waitcnt vmcnt(0)" ::: "memory");
    }
    __builtin_amdgcn_s_barrier();

    if (ch < myl) {
      const u16* Kd = &Ks[cur][0];
      const u16* Vd = &Vs[cur][0];
      const int kv0 = ch * 64;
      const bool diag = (ch == zt);

#pragma unroll
      for (int kvb = 0; kvb < 2; kvb++) {
        // ---- S^T[32kv][32q] = mfma32(K, Q) over 8 d-steps ----
        const int krow = kvb * 32 + q31;
        const u16* kr = Kd + krow * 128;
        fx16 st = zero16;
        __builtin_amdgcn_s_setprio(1);
#pragma unroll
        for (int step = 0; step < 8; step++) {
          int cs = ((step << 1) | H8) ^ (krow & 7);
          bfx8 kf = *(const bfx8*)(kr + cs * 8);
          st = __builtin_amdgcn_mfma_f32_32x32x16_bf16(kf, qf[step], st, 0, 0, 0);
        }
        __builtin_amdgcn_s_setprio(0);

        // ---- no-max softmax on lane's 16 kv values (q = q31) ----
        float pv[16];
#pragma unroll
        for (int r = 0; r < 16; r++) {
          float p = exp2f(st[r] * SC2_);
          if (diag) {
            int kvg = kv0 + kvb * 32 + (r & 3) + 8 * (r >> 2) + 4 * H8;
            p = (kvg > qg) ? 0.f : p;
          }
          l_i += p;
          pv[r] = p;
        }

        // ---- pack P^T B-frags in-register via permlane32_swap ----
#pragma unroll
        for (int half = 0; half < 2; half++) {
          const int rb = half * 8;
          u32 A0 = pk2bf(pv[rb + 0], pv[rb + 1]);
          u32 A1 = pk2bf(pv[rb + 2], pv[rb + 3]);
          u32 B0 = pk2bf(pv[rb + 4], pv[rb + 5]);
          u32 B1 = pk2bf(pv[rb + 6], pv[rb + 7]);
          asm volatile("v_permlane32_swap_b32 %0, %1" : "+v"(A0), "+v"(B0));
          asm volatile("v_permlane32_swap_b32 %0, %1" : "+v"(A1), "+v"(B1));
          union { ux4 u; bfx8 b; } pa;
          pa.u = (ux4){A0, A1, B0, B1};
          const int ks = kvb * 2 + half;  // 16-kv step index
          // ---- O^T += mfma32(V^T, P^T): lane col = own q ----
          __builtin_amdgcn_s_setprio(1);
#pragma unroll
          for (int db = 0; db < 4; db++) {
            int vrow = db * 32 + q31;
            int cv = ((ks << 1) | H8) ^ (vrow & 7);
            bfx8 vf = *(const bfx8*)(Vd + vrow * 64 + cv * 8);
            o[db] = __builtin_amdgcn_mfma_f32_32x32x16_bf16(vf, pa.b, o[db], 0, 0, 0);
          }
          __builtin_amdgcn_s_setprio(0);
        }
      }
    }
    __builtin_amdgcn_s_barrier();
    cur ^= 1;
  }

  // ---- finalize: l over lane-pair, scale, store (O rows = d, col = own q) ----
  float lt = l_i + __shfl_xor(l_i, 32);
  float inv = 1.0f / lt;
  u16* ob = Og + ((size_t)(b * T_ + qg)) * DM + h * HD;
#pragma unroll
  for (int db = 0; db < 4; db++) {
#pragma unroll
    for (int g = 0; g < 4; g++) {
      int d0 = db * 32 + 8 * g + 4 * H8;
      u32 w0 = pk2bf(o[db][4 * g + 0] * inv, o[db][4 * g + 1] * inv);
      u32 w1 = pk2bf(o[db][4 * g + 2] * inv, o[db][4 * g + 3] * inv);
      *(uint2*)(ob + d0) = make_uint2(w0, w1);
    }
  }
}

// ---------------- launch ----------------
extern "C" void kernel_launch(void* const* d_in, const int* in_sizes, int n_in,
                              void* d_out, int out_size, void* d_ws, size_t ws_size,
                              hipStream_t stream) {
  const float* x = (const float*)d_in[0];
  const float* cosp = (const float*)d_in[2];
  const float* sinp = (const float*)d_in[3];
  const float* Wq = (const float*)d_in[4];
  const float* Wk = (const float*)d_in[5];
  const float* Wv = (const float*)d_in[6];
  const float* Wo = (const float*)d_in[7];
  const float* bo = (const float*)d_in[8];
  const float* gq = (const float*)d_in[9];
  const float* gk = (const float*)d_in[10];

  char* ws = (char*)d_ws;
  u16* xbf  = (u16*)(ws + 0);           // 16 MB
  u16* wqkv = (u16*)(ws + 16777216);    // 16 MB
  u16* wo   = (u16*)(ws + 33554432);    // 8 MB
  u16* qkv  = (u16*)(ws + 41943040);    // 32 MB
  u16* qb   = (u16*)(ws + 75497472);    // 16 MB
  u16* kb   = (u16*)(ws + 92274688);    // 8 MB
  u16* vt   = (u16*)(ws + 100663296);   // 8 MB
  u16* ab   = (u16*)(ws + 109051904);   // 16 MB
  float* out = (float*)d_out;

  k_cvt<<<8192, 256, 0, stream>>>(x, xbf, 8388608);
  k_cvt<<<4096, 256, 0, stream>>>(Wq, wqkv, 4194304);
  k_cvt<<<2048, 256, 0, stream>>>(Wk, wqkv + 4194304, 2097152);
  k_cvt<<<2048, 256, 0, stream>>>(Wv, wqkv + 6291456, 2097152);
  k_cvt<<<4096, 256, 0, stream>>>(Wo, wo, 4194304);

  k_gemm256<<<256, 512, 0, stream>>>(xbf, wqkv, qkv, 4096, 4096, 2048);
  k_qkpost<<<1536, 256, 0, stream>>>(qkv, cosp, sinp, gq, gk, qb, kb);
  k_vtr<<<512, 256, 0, stream>>>(qkv, vt);
  k_attn<<<512, 256, 0, stream>>>(qb, kb, vt, ab);
  k_gemm<true><<<512, 256, 0, stream>>>(ab, wo, out, bo, 4096, 2048, 2048);
}

// Round 7
// 266.480 us; speedup vs baseline: 1.0026x; 1.0026x over previous
//
#include <hip/hip_runtime.h>
#include <stdint.h>

#define B_ 2
#define T_ 2048
#define DM 2048
#define NH 16
#define NKV 8
#define HD 128
#define NQKV 4096
#define SC2_ 0.12753102765f  // (1/sqrt(128)) * log2(e)

typedef float fx4 __attribute__((ext_vector_type(4)));
typedef float fx16 __attribute__((ext_vector_type(16)));
typedef __bf16 bfx8 __attribute__((ext_vector_type(8)));
typedef unsigned int ux4 __attribute__((ext_vector_type(4)));
typedef unsigned short u16;
typedef unsigned int u32;

typedef __attribute__((address_space(1))) const void gas_t;
typedef __attribute__((address_space(3))) void las_t;

__device__ __forceinline__ u16 f2bf(float f) {
  u32 u = __float_as_uint(f);
  u = (u + 0x7fffu + ((u >> 16) & 1u)) >> 16;
  return (u16)u;
}
__device__ __forceinline__ u32 pk2bf(float lo, float hi) {
  return (u32)f2bf(lo) | ((u32)f2bf(hi) << 16);
}

// async global->LDS, 16B per lane; lds arg must be wave-uniform base + lane*16
__device__ __forceinline__ void stage16(const void* g, void* l) {
  __builtin_amdgcn_global_load_lds((gas_t*)(uintptr_t)g, (las_t*)(uintptr_t)l,
                                   16, 0, 0);
}

// ---------------- fp32 -> bf16 convert ----------------
__global__ void k_cvt(const float* __restrict__ in, u16* __restrict__ out, int n) {
  int i = (blockIdx.x * blockDim.x + threadIdx.x) * 4;
  if (i + 3 < n) {
    float4 v = *(const float4*)(in + i);
    u32 w0 = (u32)f2bf(v.x) | ((u32)f2bf(v.y) << 16);
    u32 w1 = (u32)f2bf(v.z) | ((u32)f2bf(v.w) << 16);
    *(uint2*)(out + i) = make_uint2(w0, w1);
  }
}

// ======== 256x256 8-phase GEMM (T2+T3+T4+T5): C[M][N] = A[M][K] B[N][K]^T ========
__global__ __launch_bounds__(512, 2) void k_gemm256(const u16* __restrict__ A,
                                                    const u16* __restrict__ Bm,
                                                    u16* __restrict__ C,
                                                    int M, int N, int K) {
  __shared__ __align__(16) u16 As[2][2][256 * 32];
  __shared__ __align__(16) u16 Bs[2][2][256 * 32];
  const int nbn = N >> 8;
  const int bm = blockIdx.x / nbn, bn = blockIdx.x % nbn;
  const int tid = threadIdx.x;
  const int w = tid >> 6, lane = tid & 63;
  const int wm = w >> 2, wn = w & 3;
  const int lr = lane & 15, lg = lane >> 4;
  const int cw = (lg ^ ((lr >> 1) & 3)) * 8;
  const u16* Ab = A + (size_t)bm * 256 * K;
  const u16* Bb = Bm + (size_t)bn * 256 * K;
  const int NT = K >> 6;

  auto stage = [&](const u16* gb, u16* region, int tile, int kh) {
#pragma unroll
    for (int i = 0; i < 2; i++) {
      int q = tid + i * 512;
      int row = q >> 2, ch = q & 3;
      int sc = ch ^ ((row >> 1) & 3);
      stage16(gb + (size_t)row * K + tile * 64 + kh * 32 + sc * 8, region + q * 8);
    }
  };

  fx4 acc[8][4];
  const fx4 zero4 = {0.f, 0.f, 0.f, 0.f};
#pragma unroll
  for (int m = 0; m < 8; m++)
#pragma unroll
    for (int n = 0; n < 4; n++) acc[m][n] = zero4;

  stage(Ab, &As[0][0][0], 0, 0);
  stage(Bb, &Bs[0][0][0], 0, 0);
  stage(Ab, &As[0][1][0], 0, 1);
  stage(Bb, &Bs[0][1][0], 0, 1);
  stage(Ab, &As[1][0][0], 1, 0);
  stage(Bb, &Bs[1][0][0], 1, 0);
  asm volatile("s_waitcnt vmcnt(4)" ::: "memory");
  __builtin_amdgcn_s_barrier();

  const int arow = (wm * 128 + lr) * 32;
  const int brow = (wn * 64 + lr) * 32;
  bfx8 af[4], bf[4];

#pragma unroll 1
  for (int t = 0; t < NT; t++) {
    const u16* A0 = &As[t & 1][0][0];
    const u16* A1 = &As[t & 1][1][0];
    const u16* B0 = &Bs[t & 1][0][0];
    const u16* B1 = &Bs[t & 1][1][0];
    const int p1 = (t + 1) & 1, p2 = t & 1;

#pragma unroll
    for (int mi = 0; mi < 4; mi++) af[mi] = *(const bfx8*)(A0 + arow + mi * 512 + cw);
#pragma unroll
    for (int n = 0; n < 4; n++) bf[n] = *(const bfx8*)(B0 + brow + n * 512 + cw);
    if (t + 1 < NT) stage(Ab, &As[p1][1][0], t + 1, 1);
    __builtin_amdgcn_s_barrier();
    asm volatile("s_waitcnt lgkmcnt(0)" ::: "memory");
    __builtin_amdgcn_sched_barrier(0);
    __builtin_amdgcn_s_setprio(1);
#pragma unroll
    for (int mi = 0; mi < 4; mi++)
#pragma unroll
      for (int n = 0; n < 4; n++)
        acc[mi][n] = __builtin_amdgcn_mfma_f32_16x16x32_bf16(af[mi], bf[n], acc[mi][n], 0, 0, 0);
    __builtin_amdgcn_s_setprio(0);
    __builtin_amdgcn_s_barrier();

#pragma unroll
    for (int mi = 0; mi < 4; mi++)
      af[mi] = *(const bfx8*)(A0 + arow + 2048 + mi * 512 + cw);
    if (t + 1 < NT) stage(Bb, &Bs[p1][1][0], t + 1, 1);
    __builtin_amdgcn_s_barrier();
    asm volatile("s_waitcnt lgkmcnt(0)" ::: "memory");
    __builtin_amdgcn_sched_barrier(0);
    __builtin_amdgcn_s_setprio(1);
#pragma unroll
    for (int mi = 0; mi < 4; mi++)
#pragma unroll
      for (int n = 0; n < 4; n++)
        acc[4 + mi][n] = __builtin_amdgcn_mfma_f32_16x16x32_bf16(af[mi], bf[n], acc[4 + mi][n], 0, 0, 0);
    __builtin_amdgcn_s_setprio(0);
    __builtin_amdgcn_s_barrier();

#pragma unroll
    for (int mi = 0; mi < 4; mi++) af[mi] = *(const bfx8*)(A1 + arow + mi * 512 + cw);
#pragma unroll
    for (int n = 0; n < 4; n++) bf[n] = *(const bfx8*)(B1 + brow + n * 512 + cw);
    if (t + 2 < NT) stage(Ab, &As[p2][0][0], t + 2, 0);
    __builtin_amdgcn_s_barrier();
    asm volatile("s_waitcnt lgkmcnt(0)" ::: "memory");
    __builtin_amdgcn_sched_barrier(0);
    __builtin_amdgcn_s_setprio(1);
#pragma unroll
    for (int mi = 0; mi < 4; mi++)
#pragma unroll
      for (int n = 0; n < 4; n++)
        acc[mi][n] = __builtin_amdgcn_mfma_f32_16x16x32_bf16(af[mi], bf[n], acc[mi][n], 0, 0, 0);
    __builtin_amdgcn_s_setprio(0);
    __builtin_amdgcn_s_barrier();

#pragma unroll
    for (int mi = 0; mi < 4; mi++)
      af[mi] = *(const bfx8*)(A1 + arow + 2048 + mi * 512 + cw);
    if (t + 2 < NT) stage(Bb, &Bs[p2][0][0], t + 2, 0);
    __builtin_amdgcn_s_barrier();
    asm volatile("s_waitcnt lgkmcnt(0)" ::: "memory");
    __builtin_amdgcn_sched_barrier(0);
    __builtin_amdgcn_s_setprio(1);
#pragma unroll
    for (int mi = 0; mi < 4; mi++)
#pragma unroll
      for (int n = 0; n < 4; n++)
        acc[4 + mi][n] = __builtin_amdgcn_mfma_f32_16x16x32_bf16(af[mi], bf[n], acc[4 + mi][n], 0, 0, 0);
    __builtin_amdgcn_s_setprio(0);
    asm volatile("s_waitcnt vmcnt(4)" ::: "memory");
    __builtin_amdgcn_s_barrier();
  }

  const int r0 = bm * 256 + wm * 128, c0 = bn * 256 + wn * 64;
#pragma unroll
  for (int m = 0; m < 8; m++) {
#pragma unroll
    for (int n = 0; n < 4; n++) {
      int c = c0 + n * 16 + lr;
#pragma unroll
      for (int i = 0; i < 4; i++)
        C[(size_t)(r0 + m * 16 + lg * 4 + i) * N + c] = f2bf(acc[m][n][i]);
    }
  }
}

// ---------------- bf16 GEMM (128^2 m97-structure), used for out-proj ----------------
template <bool OUT_F32>
__global__ __launch_bounds__(256, 2) void k_gemm(const u16* __restrict__ A,
                                                 const u16* __restrict__ Bm,
                                                 void* __restrict__ Cv,
                                                 const float* __restrict__ bias,
                                                 int M, int N, int K) {
  __shared__ __align__(16) u16 As[128 * 32];
  __shared__ __align__(16) u16 Bs[128 * 32];
  const int nbn = N >> 7;
  const int bm = blockIdx.x / nbn, bn = blockIdx.x % nbn;
  const int tid = threadIdx.x;
  const int w = tid >> 6, lane = tid & 63;
  const int wr = w >> 1, wc = w & 1;
  const int lr = lane & 15, lg = lane >> 4;
  const u16* Ab = A + (size_t)bm * 128 * K;
  const u16* Bb = Bm + (size_t)bn * 128 * K;
  const int srow = lane >> 2, skc = (lane & 3) * 8;

  fx4 zero4 = {0.f, 0.f, 0.f, 0.f};
  fx4 acc[4][4];
#pragma unroll
  for (int m = 0; m < 4; m++)
#pragma unroll
    for (int n = 0; n < 4; n++) acc[m][n] = zero4;

  for (int k0 = 0; k0 < K; k0 += 32) {
#pragma unroll
    for (int t = 0; t < 2; t++) {
      int s = w + t * 4;
      stage16(Ab + (size_t)(s * 16 + srow) * K + k0 + skc, As + s * 512 + lane * 8);
      stage16(Bb + (size_t)(s * 16 + srow) * K + k0 + skc, Bs + s * 512 + lane * 8);
    }
    __syncthreads();
    bfx8 af[4], bfr[4];
#pragma unroll
    for (int m = 0; m < 4; m++)
      af[m] = *(const bfx8*)(As + (wr * 64 + m * 16 + lr) * 32 + lg * 8);
#pragma unroll
    for (int n = 0; n < 4; n++)
      bfr[n] = *(const bfx8*)(Bs + (wc * 64 + n * 16 + lr) * 32 + lg * 8);
#pragma unroll
    for (int m = 0; m < 4; m++)
#pragma unroll
      for (int n = 0; n < 4; n++)
        acc[m][n] = __builtin_amdgcn_mfma_f32_16x16x32_bf16(af[m], bfr[n], acc[m][n], 0, 0, 0);
    __syncthreads();
  }

  const int r0 = bm * 128 + wr * 64, c0 = bn * 128 + wc * 64;
#pragma unroll
  for (int m = 0; m < 4; m++) {
#pragma unroll
    for (int n = 0; n < 4; n++) {
      int c = c0 + n * 16 + lr;
#pragma unroll
      for (int i = 0; i < 4; i++) {
        int r = r0 + m * 16 + lg * 4 + i;
        if (OUT_F32) {
          ((float*)Cv)[(size_t)r * N + c] = acc[m][n][i] + bias[c];
        } else {
          ((u16*)Cv)[(size_t)r * N + c] = f2bf(acc[m][n][i]);
        }
      }
    }
  }
}

// ---------------- Q/K epilogue: rmsnorm + rope, relayout ----------------
__global__ __launch_bounds__(256) void k_qkpost(const u16* __restrict__ qkv,
                                                const float* __restrict__ cosp,
                                                const float* __restrict__ sinp,
                                                const float* __restrict__ gq,
                                                const float* __restrict__ gk,
                                                u16* __restrict__ Qo,
                                                u16* __restrict__ Ko) {
  int bi = blockIdx.x;
  int hh = bi % 24;
  int t64 = (bi / 24) % 32;
  int b = bi / 768;
  int tid = threadIdx.x;
  int j = tid >> 2, p = tid & 3;
  int t = t64 * 64 + j;
  bool isq = hh < 16;
  int colbase = isq ? hh * 128 : 2048 + (hh - 16) * 128;
  const u16* src = qkv + ((size_t)(b * T_ + t)) * NQKV + colbase + p * 32;

  float xv[32];
#pragma unroll
  for (int c = 0; c < 4; c++) {
    uint4 raw = *(const uint4*)(src + c * 8);
    u32 wd[4] = {raw.x, raw.y, raw.z, raw.w};
#pragma unroll
    for (int q2 = 0; q2 < 4; q2++) {
      xv[c * 8 + q2 * 2 + 0] = __uint_as_float(wd[q2] << 16);
      xv[c * 8 + q2 * 2 + 1] = __uint_as_float(wd[q2] & 0xffff0000u);
    }
  }
  float ss = 0.f;
#pragma unroll
  for (int i = 0; i < 32; i++) ss += xv[i] * xv[i];
  ss += __shfl_xor(ss, 1);
  ss += __shfl_xor(ss, 2);
  float rinv = rsqrtf(ss * (1.0f / 128.0f) + 1e-6f);
  const float* g = isq ? gq : gk;
  const float* cr = cosp + (size_t)t * 128 + p * 32;
  const float* sr = sinp + (size_t)t * 128 + p * 32;

  float ov[32];
#pragma unroll
  for (int i = 0; i < 32; i++) {
    float y = xv[i] * rinv * g[p * 32 + i];
    float oth = __shfl_xor(y, 2);
    float rot = (p < 2) ? -oth : oth;
    ov[i] = y * cr[i] + rot * sr[i];
  }

  uint4 pk[4];
#pragma unroll
  for (int c = 0; c < 4; c++) {
    u32 wd[4];
#pragma unroll
    for (int q2 = 0; q2 < 4; q2++)
      wd[q2] = (u32)f2bf(ov[c * 8 + q2 * 2]) | ((u32)f2bf(ov[c * 8 + q2 * 2 + 1]) << 16);
    pk[c] = make_uint4(wd[0], wd[1], wd[2], wd[3]);
  }

  if (isq) {
    u16* dst = Qo + (((size_t)(b * NH + hh)) * T_ + t) * HD + p * 32;
#pragma unroll
    for (int c = 0; c < 4; c++) *(uint4*)(dst + c * 8) = pk[c];
  } else {
    int hk = hh - 16;
    u16* dstrow = Ko + (((size_t)(b * NKV + hk)) * T_ + t) * HD;
#pragma unroll
    for (int c = 0; c < 4; c++) {
      int C = p * 4 + c;
      int Cs = C ^ (t & 7);  // XOR swizzle (16 chunks/row), matches attn read
      *(uint4*)(dstrow + Cs * 8) = pk[c];
    }
  }
}

// ---------------- V transpose: qkv[...,3072+] -> vt[b][hkv][d][t] ----------------
__global__ __launch_bounds__(256) void k_vtr(const u16* __restrict__ qkv,
                                             u16* __restrict__ vt) {
  __shared__ __align__(16) u16 sm[128 * 64];
  int bi = blockIdx.x;
  int hv = bi & 7;
  int t64 = (bi >> 3) & 31;
  int b = bi >> 8;
  int tid = threadIdx.x;
#pragma unroll
  for (int it = 0; it < 4; it++) {
    int idx = tid + it * 256;
    int tok = idx >> 4, c = idx & 15;
    uint4 raw = *(const uint4*)(qkv + ((size_t)(b * T_ + t64 * 64 + tok)) * NQKV +
                                3072 + hv * 128 + c * 8);
    u32 wd[4] = {raw.x, raw.y, raw.z, raw.w};
#pragma unroll
    for (int q2 = 0; q2 < 4; q2++) {
      sm[(c * 8 + q2 * 2 + 0) * 64 + tok] = (u16)(wd[q2] & 0xffffu);
      sm[(c * 8 + q2 * 2 + 1) * 64 + tok] = (u16)(wd[q2] >> 16);
    }
  }
  __syncthreads();
  int d = tid >> 1, half = tid & 1;
  size_t rowb = (((size_t)(b * NKV + hv)) * HD + d) * T_ + t64 * 64;
#pragma unroll
  for (int c = 0; c < 4; c++) {
    int cg = half * 4 + c;
    int cs = cg ^ (d & 7);
    u32 wd[4];
#pragma unroll
    for (int q2 = 0; q2 < 4; q2++) {
      u32 lo = sm[d * 64 + half * 32 + c * 8 + 2 * q2];
      u32 hi = sm[d * 64 + half * 32 + c * 8 + 2 * q2 + 1];
      wd[q2] = lo | (hi << 16);
    }
    *(uint4*)(vt + rowb + cs * 8) = make_uint4(wd[0], wd[1], wd[2], wd[3]);
  }
}

// ---------------- flash attention v4 (causal, GQA rep=2) ----------------
// grid = B*NH*16 = 512 blocks, 512 thr (8 waves). Wave w = (tile=w>>2,
// row_half=(w>>1)&1, kv_half=w&1). Each wave: 32 q-rows x its 32-kv half
// per chunk, 32x32 MFMA, in-register P (pk+permlane), no-max softmax
// (linear -> kv-half partials combine by addition via LDS at the end,
// reusing K/V buffers). Round-5 staging/counted-vmcnt schedule.
__global__ __launch_bounds__(512, 2) void k_attn(const u16* __restrict__ Qg,
                                                 const u16* __restrict__ Kg,
                                                 const u16* __restrict__ Vg,
                                                 u16* __restrict__ Og) {
  __shared__ __align__(16) u16 Ks[2][64 * 128];
  __shared__ __align__(16) u16 Vs[2][128 * 64];
  __shared__ float lb[4][32];
  const int bi = blockIdx.x;
  const int zr = bi & 15, h = (bi >> 4) & 15, b = bi >> 8;
  const int z = b ? (15 - zr) : zr;  // heavy+light pairing across grid halves
  const int hkv = h >> 1;
  const int tid = threadIdx.x, w = tid >> 6, lane = tid & 63;
  const int q31 = lane & 31, H8 = lane >> 5;
  const int kvh = w & 1, rh = (w >> 1) & 1, thi = w >> 2;
  const int zt = thi ? (31 - z) : z;
  const int qr0 = zt * 64 + rh * 32;
  const int qg = qr0 + q31;
  const int nch = 32 - z;
  const int myl = zt + 1;
  const int pair = w >> 1;  // combine-pair id (tile,rh)

  const u16* kb = Kg + ((size_t)(b * NKV + hkv)) * T_ * HD;
  const u16* vb = Vg + ((size_t)(b * NKV + hkv)) * HD * T_;

  // Q regs: B-frag per 16-d step: lane holds Q[qg][d = step*16 + 8*H8 + j]
  const u16* qrow = Qg + (((size_t)(b * NH + h)) * T_ + qg) * HD;
  bfx8 qf[8];
#pragma unroll
  for (int step = 0; step < 8; step++)
    qf[step] = *(const bfx8*)(qrow + step * 16 + H8 * 8);

  fx16 o[4];
  const fx16 zero16 = {0.f, 0.f, 0.f, 0.f, 0.f, 0.f, 0.f, 0.f,
                       0.f, 0.f, 0.f, 0.f, 0.f, 0.f, 0.f, 0.f};
#pragma unroll
  for (int db = 0; db < 4; db++) o[db] = zero16;
  float l_i = 0.f;

  // 512 threads stage K[64][128] + V[128][64] (32KB): 4 x 16B per thread.
  auto stageKV = [&](int buf, int kv0) {
    u16* Kd = &Ks[buf][0];
    u16* Vd = &Vs[buf][0];
#pragma unroll
    for (int it = 0; it < 2; it++) {
      int r = it * 32 + (tid >> 4);
      stage16(kb + (size_t)(kv0 + r) * HD + (tid & 15) * 8, Kd + it * 4096 + tid * 8);
      int d = it * 64 + (tid >> 3);
      stage16(vb + (size_t)d * T_ + kv0 + (tid & 7) * 8, Vd + it * 4096 + tid * 8);
    }
  };

  stageKV(0, 0);
  asm volatile("s_waitcnt vmcnt(0)" ::: "memory");
  __builtin_amdgcn_s_barrier();
  int cur = 0;

#pragma unroll 1
  for (int ch = 0; ch < nch; ch++) {
    if (ch + 1 < nch) {
      stageKV(cur ^ 1, (ch + 1) * 64);
      asm volatile("s_waitcnt vmcnt(4)" ::: "memory");
    } else {
      asm volatile("s_waitcnt vmcnt(0)" ::: "memory");
    }
    __builtin_amdgcn_s_barrier();

    if (ch < myl) {
      const u16* Kd = &Ks[cur][0];
      const u16* Vd = &Vs[cur][0];
      const int kv0 = ch * 64;
      const bool diag = (ch == zt);

      // ---- S^T[32kv-half][32q] = mfma32(K, Q) over 8 d-steps ----
      const int krow = kvh * 32 + q31;
      const u16* kr = Kd + krow * 128;
      fx16 st = zero16;
      __builtin_amdgcn_s_setprio(1);
#pragma unroll
      for (int step = 0; step < 8; step++) {
        int cs = ((step << 1) | H8) ^ (krow & 7);
        bfx8 kf = *(const bfx8*)(kr + cs * 8);
        st = __builtin_amdgcn_mfma_f32_32x32x16_bf16(kf, qf[step], st, 0, 0, 0);
      }
      __builtin_amdgcn_s_setprio(0);

      // ---- no-max softmax on lane's 16 kv values ----
      float pv[16];
#pragma unroll
      for (int r = 0; r < 16; r++) {
        float p = exp2f(st[r] * SC2_);
        if (diag) {
          int kvg = kv0 + kvh * 32 + (r & 3) + 8 * (r >> 2) + 4 * H8;
          p = (kvg > qg) ? 0.f : p;
        }
        l_i += p;
        pv[r] = p;
      }

      // ---- pack P^T B-frags in-register via permlane32_swap ----
#pragma unroll
      for (int half = 0; half < 2; half++) {
        const int rb = half * 8;
        u32 A0 = pk2bf(pv[rb + 0], pv[rb + 1]);
        u32 A1 = pk2bf(pv[rb + 2], pv[rb + 3]);
        u32 B0 = pk2bf(pv[rb + 4], pv[rb + 5]);
        u32 B1 = pk2bf(pv[rb + 6], pv[rb + 7]);
        asm volatile("v_permlane32_swap_b32 %0, %1" : "+v"(A0), "+v"(B0));
        asm volatile("v_permlane32_swap_b32 %0, %1" : "+v"(A1), "+v"(B1));
        union { ux4 u; bfx8 b; } pa;
        pa.u = (ux4){A0, A1, B0, B1};
        const int ks = kvh * 2 + half;  // 16-kv step index within chunk
        __builtin_amdgcn_s_setprio(1);
#pragma unroll
        for (int db = 0; db < 4; db++) {
          int vrow = db * 32 + q31;
          int cv = ((ks << 1) | H8) ^ (vrow & 7);
          bfx8 vf = *(const bfx8*)(Vd + vrow * 64 + cv * 8);
          o[db] = __builtin_amdgcn_mfma_f32_32x32x16_bf16(vf, pa.b, o[db], 0, 0, 0);
        }
        __builtin_amdgcn_s_setprio(0);
      }
    }
    __builtin_amdgcn_s_barrier();
    cur ^= 1;
  }

  // ---- combine kv-half partials (o,l are LINEAR sums) via LDS ----
  float lt = l_i + __shfl_xor(l_i, 32);
  float* cb = (pair < 2) ? ((float*)&Ks[0][0] + pair * 4096)
                         : ((float*)&Vs[0][0] + (pair - 2) * 4096);
  if (kvh == 1) {
    if (H8 == 0) lb[pair][q31] = lt;
#pragma unroll
    for (int db = 0; db < 4; db++)
#pragma unroll
      for (int g = 0; g < 4; g++) {
        int dofs = (db * 32 + 8 * g + 4 * H8) ^ ((q31 & 7) << 2);
        *(fx4*)(cb + q31 * 128 + dofs) =
            (fx4){o[db][4 * g], o[db][4 * g + 1], o[db][4 * g + 2], o[db][4 * g + 3]};
      }
  }
  __syncthreads();
  if (kvh == 0) {
    float inv = 1.0f / (lt + lb[pair][q31]);
    u16* ob = Og + ((size_t)(b * T_ + qg)) * DM + h * HD;
#pragma unroll
    for (int db = 0; db < 4; db++) {
#pragma unroll
      for (int g = 0; g < 4; g++) {
        int dofs = (db * 32 + 8 * g + 4 * H8) ^ ((q31 & 7) << 2);
        fx4 op = *(const fx4*)(cb + q31 * 128 + dofs);
        int d0 = db * 32 + 8 * g + 4 * H8;
        u32 w0 = pk2bf((o[db][4 * g] + op[0]) * inv, (o[db][4 * g + 1] + op[1]) * inv);
        u32 w1 = pk2bf((o[db][4 * g + 2] + op[2]) * inv, (o[db][4 * g + 3] + op[3]) * inv);
        *(uint2*)(ob + d0) = make_uint2(w0, w1);
      }
    }
  }
}

// ---------------- launch ----------------
extern "C" void kernel_launch(void* const* d_in, const int* in_sizes, int n_in,
                              void* d_out, int out_size, void* d_ws, size_t ws_size,
                              hipStream_t stream) {
  const float* x = (const float*)d_in[0];
  const float* cosp = (const float*)d_in[2];
  const float* sinp = (const float*)d_in[3];
  const float* Wq = (const float*)d_in[4];
  const float* Wk = (const float*)d_in[5];
  const float* Wv = (const float*)d_in[6];
  const float* Wo = (const float*)d_in[7];
  const float* bo = (const float*)d_in[8];
  const float* gq = (const float*)d_in[9];
  const float* gk = (const float*)d_in[10];

  char* ws = (char*)d_ws;
  u16* xbf  = (u16*)(ws + 0);           // 16 MB
  u16* wqkv = (u16*)(ws + 16777216);    // 16 MB
  u16* wo   = (u16*)(ws + 33554432);    // 8 MB
  u16* qkv  = (u16*)(ws + 41943040);    // 32 MB
  u16* qb   = (u16*)(ws + 75497472);    // 16 MB
  u16* kb   = (u16*)(ws + 92274688);    // 8 MB
  u16* vt   = (u16*)(ws + 100663296);   // 8 MB
  u16* ab   = (u16*)(ws + 109051904);   // 16 MB
  float* out = (float*)d_out;

  k_cvt<<<8192, 256, 0, stream>>>(x, xbf, 8388608);
  k_cvt<<<4096, 256, 0, stream>>>(Wq, wqkv, 4194304);
  k_cvt<<<2048, 256, 0, stream>>>(Wk, wqkv + 4194304, 2097152);
  k_cvt<<<2048, 256, 0, stream>>>(Wv, wqkv + 6291456, 2097152);
  k_cvt<<<4096, 256, 0, stream>>>(Wo, wo, 4194304);

  k_gemm256<<<256, 512, 0, stream>>>(xbf, wqkv, qkv, 4096, 4096, 2048);
  k_qkpost<<<1536, 256, 0, stream>>>(qkv, cosp, sinp, gq, gk, qb, kb);
  k_vtr<<<512, 256, 0, stream>>>(qkv, vt);
  k_attn<<<512, 512, 0, stream>>>(qb, kb, vt, ab);
  k_gemm<true><<<512, 256, 0, stream>>>(ab, wo, out, bo, 4096, 2048, 2048);
}

// Round 10
// 243.321 us; speedup vs baseline: 1.0980x; 1.0952x over previous
//
#include <hip/hip_runtime.h>
#include <stdint.h>

#define B_ 2
#define T_ 2048
#define DM 2048
#define NH 16
#define NKV 8
#define HD 128
#define NQKV 4096
#define SC2_ 0.12753102765f  // (1/sqrt(128)) * log2(e)

typedef float fx4 __attribute__((ext_vector_type(4)));
typedef __bf16 bfx8 __attribute__((ext_vector_type(8)));
typedef unsigned short u16;
typedef unsigned int u32;

typedef __attribute__((address_space(1))) const void gas_t;
typedef __attribute__((address_space(3))) void las_t;

__device__ __forceinline__ u16 f2bf(float f) {
  u32 u = __float_as_uint(f);
  u = (u + 0x7fffu + ((u >> 16) & 1u)) >> 16;
  return (u16)u;
}

// async global->LDS, 16B per lane; lds arg must be wave-uniform base + lane*16
__device__ __forceinline__ void stage16(const void* g, void* l) {
  __builtin_amdgcn_global_load_lds((gas_t*)(uintptr_t)g, (las_t*)(uintptr_t)l,
                                   16, 0, 0);
}

// ---------------- fp32 -> bf16 convert ----------------
__global__ void k_cvt(const float* __restrict__ in, u16* __restrict__ out, int n) {
  int i = (blockIdx.x * blockDim.x + threadIdx.x) * 4;
  if (i + 3 < n) {
    float4 v = *(const float4*)(in + i);
    u32 w0 = (u32)f2bf(v.x) | ((u32)f2bf(v.y) << 16);
    u32 w1 = (u32)f2bf(v.z) | ((u32)f2bf(v.w) << 16);
    *(uint2*)(out + i) = make_uint2(w0, w1);
  }
}

// ======== 256x256 8-phase GEMM (T2+T3+T4+T5): C[M][N] = A[M][K] B[N][K]^T ========
// Epilogue-race fix: end-of-tile waits vmcnt(0) when no t+2 stage was issued,
// so the last tile's kh1 stages are guaranteed landed before their reads.
__global__ __launch_bounds__(512, 2) void k_gemm256(const u16* __restrict__ A,
                                                    const u16* __restrict__ Bm,
                                                    u16* __restrict__ C,
                                                    int M, int N, int K) {
  __shared__ __align__(16) u16 As[2][2][256 * 32];
  __shared__ __align__(16) u16 Bs[2][2][256 * 32];
  const int nbn = N >> 8;
  const int bm = blockIdx.x / nbn, bn = blockIdx.x % nbn;
  const int tid = threadIdx.x;
  const int w = tid >> 6, lane = tid & 63;
  const int wm = w >> 2, wn = w & 3;
  const int lr = lane & 15, lg = lane >> 4;
  const int cw = (lg ^ ((lr >> 1) & 3)) * 8;
  const u16* Ab = A + (size_t)bm * 256 * K;
  const u16* Bb = Bm + (size_t)bn * 256 * K;
  const int NT = K >> 6;

  auto stage = [&](const u16* gb, u16* region, int tile, int kh) {
#pragma unroll
    for (int i = 0; i < 2; i++) {
      int q = tid + i * 512;
      int row = q >> 2, ch = q & 3;
      int sc = ch ^ ((row >> 1) & 3);
      stage16(gb + (size_t)row * K + tile * 64 + kh * 32 + sc * 8, region + q * 8);
    }
  };

  fx4 acc[8][4];
  const fx4 zero4 = {0.f, 0.f, 0.f, 0.f};
#pragma unroll
  for (int m = 0; m < 8; m++)
#pragma unroll
    for (int n = 0; n < 4; n++) acc[m][n] = zero4;

  stage(Ab, &As[0][0][0], 0, 0);
  stage(Bb, &Bs[0][0][0], 0, 0);
  stage(Ab, &As[0][1][0], 0, 1);
  stage(Bb, &Bs[0][1][0], 0, 1);
  stage(Ab, &As[1][0][0], 1, 0);
  stage(Bb, &Bs[1][0][0], 1, 0);
  asm volatile("s_waitcnt vmcnt(4)" ::: "memory");
  __builtin_amdgcn_s_barrier();

  const int arow = (wm * 128 + lr) * 32;
  const int brow = (wn * 64 + lr) * 32;
  bfx8 af[4], bf[4];

#pragma unroll 1
  for (int t = 0; t < NT; t++) {
    const u16* A0 = &As[t & 1][0][0];
    const u16* A1 = &As[t & 1][1][0];
    const u16* B0 = &Bs[t & 1][0][0];
    const u16* B1 = &Bs[t & 1][1][0];
    const int p1 = (t + 1) & 1, p2 = t & 1;

#pragma unroll
    for (int mi = 0; mi < 4; mi++) af[mi] = *(const bfx8*)(A0 + arow + mi * 512 + cw);
#pragma unroll
    for (int n = 0; n < 4; n++) bf[n] = *(const bfx8*)(B0 + brow + n * 512 + cw);
    if (t + 1 < NT) stage(Ab, &As[p1][1][0], t + 1, 1);
    __builtin_amdgcn_s_barrier();
    asm volatile("s_waitcnt lgkmcnt(0)" ::: "memory");
    __builtin_amdgcn_sched_barrier(0);
    __builtin_amdgcn_s_setprio(1);
#pragma unroll
    for (int mi = 0; mi < 4; mi++)
#pragma unroll
      for (int n = 0; n < 4; n++)
        acc[mi][n] = __builtin_amdgcn_mfma_f32_16x16x32_bf16(af[mi], bf[n], acc[mi][n], 0, 0, 0);
    __builtin_amdgcn_s_setprio(0);
    __builtin_amdgcn_s_barrier();

#pragma unroll
    for (int mi = 0; mi < 4; mi++)
      af[mi] = *(const bfx8*)(A0 + arow + 2048 + mi * 512 + cw);
    if (t + 1 < NT) stage(Bb, &Bs[p1][1][0], t + 1, 1);
    __builtin_amdgcn_s_barrier();
    asm volatile("s_waitcnt lgkmcnt(0)" ::: "memory");
    __builtin_amdgcn_sched_barrier(0);
    __builtin_amdgcn_s_setprio(1);
#pragma unroll
    for (int mi = 0; mi < 4; mi++)
#pragma unroll
      for (int n = 0; n < 4; n++)
        acc[4 + mi][n] = __builtin_amdgcn_mfma_f32_16x16x32_bf16(af[mi], bf[n], acc[4 + mi][n], 0, 0, 0);
    __builtin_amdgcn_s_setprio(0);
    __builtin_amdgcn_s_barrier();

#pragma unroll
    for (int mi = 0; mi < 4; mi++) af[mi] = *(const bfx8*)(A1 + arow + mi * 512 + cw);
#pragma unroll
    for (int n = 0; n < 4; n++) bf[n] = *(const bfx8*)(B1 + brow + n * 512 + cw);
    if (t + 2 < NT) stage(Ab, &As[p2][0][0], t + 2, 0);
    __builtin_amdgcn_s_barrier();
    asm volatile("s_waitcnt lgkmcnt(0)" ::: "memory");
    __builtin_amdgcn_sched_barrier(0);
    __builtin_amdgcn_s_setprio(1);
#pragma unroll
    for (int mi = 0; mi < 4; mi++)
#pragma unroll
      for (int n = 0; n < 4; n++)
        acc[mi][n] = __builtin_amdgcn_mfma_f32_16x16x32_bf16(af[mi], bf[n], acc[mi][n], 0, 0, 0);
    __builtin_amdgcn_s_setprio(0);
    __builtin_amdgcn_s_barrier();

#pragma unroll
    for (int mi = 0; mi < 4; mi++)
      af[mi] = *(const bfx8*)(A1 + arow + 2048 + mi * 512 + cw);
    if (t + 2 < NT) stage(Bb, &Bs[p2][0][0], t + 2, 0);
    __builtin_amdgcn_s_barrier();
    asm volatile("s_waitcnt lgkmcnt(0)" ::: "memory");
    __builtin_amdgcn_sched_barrier(0);
    __builtin_amdgcn_s_setprio(1);
#pragma unroll
    for (int mi = 0; mi < 4; mi++)
#pragma unroll
      for (int n = 0; n < 4; n++)
        acc[4 + mi][n] = __builtin_amdgcn_mfma_f32_16x16x32_bf16(af[mi], bf[n], acc[4 + mi][n], 0, 0, 0);
    __builtin_amdgcn_s_setprio(0);
    if (t + 2 < NT) {
      asm volatile("s_waitcnt vmcnt(4)" ::: "memory");
    } else {
      // no t+2 stages were issued this tile: drain EVERYTHING so the last
      // tile's kh1 (staged this tile / earlier) is guaranteed landed.
      asm volatile("s_waitcnt vmcnt(0)" ::: "memory");
    }
    __builtin_amdgcn_s_barrier();
  }

  const int r0 = bm * 256 + wm * 128, c0 = bn * 256 + wn * 64;
#pragma unroll
  for (int m = 0; m < 8; m++) {
#pragma unroll
    for (int n = 0; n < 4; n++) {
      int c = c0 + n * 16 + lr;
#pragma unroll
      for (int i = 0; i < 4; i++)
        C[(size_t)(r0 + m * 16 + lg * 4 + i) * N + c] = f2bf(acc[m][n][i]);
    }
  }
}

// ======== 128x128 8-phase GEMM, f32+bias out (out-proj) ========
// Same schedule as k_gemm256 scaled to 256 thr / 4 waves (2Mx2N), BK=64.
// Epilogue-race fix applied (vmcnt(0) on the no-stage tail tiles).
__global__ __launch_bounds__(256, 2) void k_gemmo(const u16* __restrict__ A,
                                                  const u16* __restrict__ Bm,
                                                  float* __restrict__ C,
                                                  const float* __restrict__ bias,
                                                  int M, int N, int K) {
  __shared__ __align__(16) u16 As[2][2][128 * 32];
  __shared__ __align__(16) u16 Bs[2][2][128 * 32];
  const int nbn = N >> 7;
  const int bm = blockIdx.x / nbn, bn = blockIdx.x % nbn;
  const int tid = threadIdx.x;
  const int w = tid >> 6, lane = tid & 63;
  const int wm = w >> 1, wn = w & 1;
  const int lr = lane & 15, lg = lane >> 4;
  const int cw = (lg ^ ((lr >> 1) & 3)) * 8;
  const u16* Ab = A + (size_t)bm * 128 * K;
  const u16* Bb = Bm + (size_t)bn * 128 * K;
  const int NT = K >> 6;

  auto stage = [&](const u16* gb, u16* region, int tile, int kh) {
#pragma unroll
    for (int i = 0; i < 2; i++) {
      int q = tid + i * 256;
      int row = q >> 2, ch = q & 3;
      int sc = ch ^ ((row >> 1) & 3);
      stage16(gb + (size_t)row * K + tile * 64 + kh * 32 + sc * 8, region + q * 8);
    }
  };

  fx4 acc[4][4];
  const fx4 zero4 = {0.f, 0.f, 0.f, 0.f};
#pragma unroll
  for (int m = 0; m < 4; m++)
#pragma unroll
    for (int n = 0; n < 4; n++) acc[m][n] = zero4;

  stage(Ab, &As[0][0][0], 0, 0);
  stage(Bb, &Bs[0][0][0], 0, 0);
  stage(Ab, &As[0][1][0], 0, 1);
  stage(Bb, &Bs[0][1][0], 0, 1);
  stage(Ab, &As[1][0][0], 1, 0);
  stage(Bb, &Bs[1][0][0], 1, 0);
  asm volatile("s_waitcnt vmcnt(4)" ::: "memory");
  __builtin_amdgcn_s_barrier();

  const int arow = (wm * 64 + lr) * 32;
  const int brow = (wn * 64 + lr) * 32;
  bfx8 af[2], bf[4];

#pragma unroll 1
  for (int t = 0; t < NT; t++) {
    const u16* A0 = &As[t & 1][0][0];
    const u16* A1 = &As[t & 1][1][0];
    const u16* B0 = &Bs[t & 1][0][0];
    const u16* B1 = &Bs[t & 1][1][0];
    const int p1 = (t + 1) & 1, p2 = t & 1;

    // phase 0: kh0, m-half 0
#pragma unroll
    for (int mi = 0; mi < 2; mi++) af[mi] = *(const bfx8*)(A0 + arow + mi * 512 + cw);
#pragma unroll
    for (int n = 0; n < 4; n++) bf[n] = *(const bfx8*)(B0 + brow + n * 512 + cw);
    if (t + 1 < NT) stage(Ab, &As[p1][1][0], t + 1, 1);
    __builtin_amdgcn_s_barrier();
    asm volatile("s_waitcnt lgkmcnt(0)" ::: "memory");
    __builtin_amdgcn_sched_barrier(0);
    __builtin_amdgcn_s_setprio(1);
#pragma unroll
    for (int mi = 0; mi < 2; mi++)
#pragma unroll
      for (int n = 0; n < 4; n++)
        acc[mi][n] = __builtin_amdgcn_mfma_f32_16x16x32_bf16(af[mi], bf[n], acc[mi][n], 0, 0, 0);
    __builtin_amdgcn_s_setprio(0);
    __builtin_amdgcn_s_barrier();

    // phase 1: kh0, m-half 1
#pragma unroll
    for (int mi = 0; mi < 2; mi++)
      af[mi] = *(const bfx8*)(A0 + arow + 1024 + mi * 512 + cw);
    if (t + 1 < NT) stage(Bb, &Bs[p1][1][0], t + 1, 1);
    __builtin_amdgcn_s_barrier();
    asm volatile("s_waitcnt lgkmcnt(0)" ::: "memory");
    __builtin_amdgcn_sched_barrier(0);
    __builtin_amdgcn_s_setprio(1);
#pragma unroll
    for (int mi = 0; mi < 2; mi++)
#pragma unroll
      for (int n = 0; n < 4; n++)
        acc[2 + mi][n] = __builtin_amdgcn_mfma_f32_16x16x32_bf16(af[mi], bf[n], acc[2 + mi][n], 0, 0, 0);
    __builtin_amdgcn_s_setprio(0);
    __builtin_amdgcn_s_barrier();

    // phase 2: kh1, m-half 0
#pragma unroll
    for (int mi = 0; mi < 2; mi++) af[mi] = *(const bfx8*)(A1 + arow + mi * 512 + cw);
#pragma unroll
    for (int n = 0; n < 4; n++) bf[n] = *(const bfx8*)(B1 + brow + n * 512 + cw);
    if (t + 2 < NT) stage(Ab, &As[p2][0][0], t + 2, 0);
    __builtin_amdgcn_s_barrier();
    asm volatile("s_waitcnt lgkmcnt(0)" ::: "memory");
    __builtin_amdgcn_sched_barrier(0);
    __builtin_amdgcn_s_setprio(1);
#pragma unroll
    for (int mi = 0; mi < 2; mi++)
#pragma unroll
      for (int n = 0; n < 4; n++)
        acc[mi][n] = __builtin_amdgcn_mfma_f32_16x16x32_bf16(af[mi], bf[n], acc[mi][n], 0, 0, 0);
    __builtin_amdgcn_s_setprio(0);
    __builtin_amdgcn_s_barrier();

    // phase 3: kh1, m-half 1
#pragma unroll
    for (int mi = 0; mi < 2; mi++)
      af[mi] = *(const bfx8*)(A1 + arow + 1024 + mi * 512 + cw);
    if (t + 2 < NT) stage(Bb, &Bs[p2][0][0], t + 2, 0);
    __builtin_amdgcn_s_barrier();
    asm volatile("s_waitcnt lgkmcnt(0)" ::: "memory");
    __builtin_amdgcn_sched_barrier(0);
    __builtin_amdgcn_s_setprio(1);
#pragma unroll
    for (int mi = 0; mi < 2; mi++)
#pragma unroll
      for (int n = 0; n < 4; n++)
        acc[2 + mi][n] = __builtin_amdgcn_mfma_f32_16x16x32_bf16(af[mi], bf[n], acc[2 + mi][n], 0, 0, 0);
    __builtin_amdgcn_s_setprio(0);
    if (t + 2 < NT) {
      asm volatile("s_waitcnt vmcnt(4)" ::: "memory");
    } else {
      // RACE FIX: tile NT-2 issues no t+2 stages, so vmcnt(4) would leave
      // the LAST tile's kh1 stages in flight; drain fully instead.
      asm volatile("s_waitcnt vmcnt(0)" ::: "memory");
    }
    __builtin_amdgcn_s_barrier();
  }

  const int r0 = bm * 128 + wm * 64, c0 = bn * 128 + wn * 64;
#pragma unroll
  for (int m = 0; m < 4; m++) {
#pragma unroll
    for (int n = 0; n < 4; n++) {
      int c = c0 + n * 16 + lr;
#pragma unroll
      for (int i = 0; i < 4; i++)
        C[(size_t)(r0 + m * 16 + lg * 4 + i) * N + c] = acc[m][n][i] + bias[c];
    }
  }
}

// ---------------- Q/K epilogue: rmsnorm + rope, relayout ----------------
__global__ __launch_bounds__(256) void k_qkpost(const u16* __restrict__ qkv,
                                                const float* __restrict__ cosp,
                                                const float* __restrict__ sinp,
                                                const float* __restrict__ gq,
                                                const float* __restrict__ gk,
                                                u16* __restrict__ Qo,
                                                u16* __restrict__ Ko) {
  int bi = blockIdx.x;
  int hh = bi % 24;
  int t64 = (bi / 24) % 32;
  int b = bi / 768;
  int tid = threadIdx.x;
  int j = tid >> 2, p = tid & 3;
  int t = t64 * 64 + j;
  bool isq = hh < 16;
  int colbase = isq ? hh * 128 : 2048 + (hh - 16) * 128;
  const u16* src = qkv + ((size_t)(b * T_ + t)) * NQKV + colbase + p * 32;

  float xv[32];
#pragma unroll
  for (int c = 0; c < 4; c++) {
    uint4 raw = *(const uint4*)(src + c * 8);
    u32 wd[4] = {raw.x, raw.y, raw.z, raw.w};
#pragma unroll
    for (int q2 = 0; q2 < 4; q2++) {
      xv[c * 8 + q2 * 2 + 0] = __uint_as_float(wd[q2] << 16);
      xv[c * 8 + q2 * 2 + 1] = __uint_as_float(wd[q2] & 0xffff0000u);
    }
  }
  float ss = 0.f;
#pragma unroll
  for (int i = 0; i < 32; i++) ss += xv[i] * xv[i];
  ss += __shfl_xor(ss, 1);
  ss += __shfl_xor(ss, 2);
  float rinv = rsqrtf(ss * (1.0f / 128.0f) + 1e-6f);
  const float* g = isq ? gq : gk;
  const float* cr = cosp + (size_t)t * 128 + p * 32;
  const float* sr = sinp + (size_t)t * 128 + p * 32;

  float ov[32];
#pragma unroll
  for (int i = 0; i < 32; i++) {
    float y = xv[i] * rinv * g[p * 32 + i];
    float oth = __shfl_xor(y, 2);
    float rot = (p < 2) ? -oth : oth;
    ov[i] = y * cr[i] + rot * sr[i];
  }

  uint4 pk[4];
#pragma unroll
  for (int c = 0; c < 4; c++) {
    u32 wd[4];
#pragma unroll
    for (int q2 = 0; q2 < 4; q2++)
      wd[q2] = (u32)f2bf(ov[c * 8 + q2 * 2]) | ((u32)f2bf(ov[c * 8 + q2 * 2 + 1]) << 16);
    pk[c] = make_uint4(wd[0], wd[1], wd[2], wd[3]);
  }

  if (isq) {
    u16* dst = Qo + (((size_t)(b * NH + hh)) * T_ + t) * HD + p * 32;
#pragma unroll
    for (int c = 0; c < 4; c++) *(uint4*)(dst + c * 8) = pk[c];
  } else {
    int hk = hh - 16;
    u16* dstrow = Ko + (((size_t)(b * NKV + hk)) * T_ + t) * HD;
#pragma unroll
    for (int c = 0; c < 4; c++) {
      int C = p * 4 + c;
      int Cs = C ^ (t & 7);  // XOR swizzle (16 chunks/row), matches attn read
      *(uint4*)(dstrow + Cs * 8) = pk[c];
    }
  }
}

// ---------------- V transpose: qkv[...,3072+] -> vt[b][hkv][d][t] ----------------
__global__ __launch_bounds__(256) void k_vtr(const u16* __restrict__ qkv,
                                             u16* __restrict__ vt) {
  __shared__ __align__(16) u16 sm[128 * 64];
  int bi = blockIdx.x;
  int hv = bi & 7;
  int t64 = (bi >> 3) & 31;
  int b = bi >> 8;
  int tid = threadIdx.x;
#pragma unroll
  for (int it = 0; it < 4; it++) {
    int idx = tid + it * 256;
    int tok = idx >> 4, c = idx & 15;
    uint4 raw = *(const uint4*)(qkv + ((size_t)(b * T_ + t64 * 64 + tok)) * NQKV +
                                3072 + hv * 128 + c * 8);
    u32 wd[4] = {raw.x, raw.y, raw.z, raw.w};
#pragma unroll
    for (int q2 = 0; q2 < 4; q2++) {
      sm[(c * 8 + q2 * 2 + 0) * 64 + tok] = (u16)(wd[q2] & 0xffffu);
      sm[(c * 8 + q2 * 2 + 1) * 64 + tok] = (u16)(wd[q2] >> 16);
    }
  }
  __syncthreads();
  int d = tid >> 1, half = tid & 1;
  size_t rowb = (((size_t)(b * NKV + hv)) * HD + d) * T_ + t64 * 64;
#pragma unroll
  for (int c = 0; c < 4; c++) {
    int cg = half * 4 + c;
    int cs = cg ^ (d & 7);
    u32 wd[4];
#pragma unroll
    for (int q2 = 0; q2 < 4; q2++) {
      u32 lo = sm[d * 64 + half * 32 + c * 8 + 2 * q2];
      u32 hi = sm[d * 64 + half * 32 + c * 8 + 2 * q2 + 1];
      wd[q2] = lo | (hi << 16);
    }
    *(uint4*)(vt + rowb + cs * 8) = make_uint4(wd[0], wd[1], wd[2], wd[3]);
  }
}

// ---------------- flash attention (round-5 kernel, PROVEN: 81us, passed) ----------
__global__ __launch_bounds__(512, 4) void k_attn(const u16* __restrict__ Qg,
                                                 const u16* __restrict__ Kg,
                                                 const u16* __restrict__ Vg,
                                                 u16* __restrict__ Og) {
  __shared__ __align__(16) u16 Ks[2][64 * 128];
  __shared__ __align__(16) u16 Vs[2][128 * 64];
  __shared__ __align__(16) u16 Ps[8][16 * 64];
  const int bi = blockIdx.x;
  const int zr = bi & 15, h = (bi >> 4) & 15, b = bi >> 8;
  const int z = b ? (15 - zr) : zr;
  const int hkv = h >> 1;
  const int tid = threadIdx.x, w = tid >> 6, lane = tid & 63;
  const int lr = lane & 15, lg = lane >> 4;
  const int zt = (w < 4) ? z : (31 - z);
  const int qr0 = zt * 64 + (w & 3) * 16;
  const int nch = 32 - z;
  const int myl = zt + 1;

  const u16* kb = Kg + ((size_t)(b * NKV + hkv)) * T_ * HD;
  const u16* vb = Vg + ((size_t)(b * NKV + hkv)) * HD * T_;
  u16* pw = &Ps[w][0];
  const fx4 zero4 = {0.f, 0.f, 0.f, 0.f};

  auto stageKV = [&](int buf, int kv0) {
    u16* Kd = &Ks[buf][0];
    u16* Vd = &Vs[buf][0];
#pragma unroll
    for (int it = 0; it < 2; it++) {
      int r = it * 32 + (tid >> 4);
      stage16(kb + (size_t)(kv0 + r) * HD + (tid & 15) * 8, Kd + it * 4096 + tid * 8);
      int d = it * 64 + (tid >> 3);
      stage16(vb + (size_t)d * T_ + kv0 + (tid & 7) * 8, Vd + it * 4096 + tid * 8);
    }
  };

  const u16* qbase = Qg + (((size_t)(b * NH + h)) * T_ + qr0 + lr) * HD;
  bfx8 qf[4];
#pragma unroll
  for (int kk = 0; kk < 4; kk++) qf[kk] = *(const bfx8*)(qbase + kk * 32 + lg * 8);

  fx4 o[8];
#pragma unroll
  for (int nf = 0; nf < 8; nf++) o[nf] = zero4;
  float l_i[4] = {0.f, 0.f, 0.f, 0.f};

  stageKV(0, 0);
  asm volatile("s_waitcnt vmcnt(0)" ::: "memory");
  __builtin_amdgcn_s_barrier();
  int cur = 0;

#pragma unroll 1
  for (int ch = 0; ch < nch; ch++) {
    if (ch + 1 < nch) {
      stageKV(cur ^ 1, (ch + 1) * 64);
      asm volatile("s_waitcnt vmcnt(4)" ::: "memory");
    } else {
      asm volatile("s_waitcnt vmcnt(0)" ::: "memory");
    }
    __builtin_amdgcn_s_barrier();

    if (ch < myl) {
      const u16* Kd = &Ks[cur][0];
      const u16* Vd = &Vs[cur][0];
      const int kv0 = ch * 64;
      const bool diag = (ch == zt);

      fx4 sa[4];
#pragma unroll
      for (int n = 0; n < 4; n++) sa[n] = zero4;
      __builtin_amdgcn_s_setprio(1);
#pragma unroll
      for (int n = 0; n < 4; n++) {
        const int kvl = n * 16 + lr;
        const u16* krow = Kd + kvl * 128;
#pragma unroll
        for (int kk = 0; kk < 4; kk++) {
          int cs = (kk * 4 + lg) ^ (kvl & 7);
          bfx8 kf = *(const bfx8*)(krow + cs * 8);
          sa[n] = __builtin_amdgcn_mfma_f32_16x16x32_bf16(qf[kk], kf, sa[n], 0, 0, 0);
        }
      }
      __builtin_amdgcn_s_setprio(0);

#pragma unroll
      for (int i = 0; i < 4; i++) {
        const int q = 4 * lg + i;
        const int r = qr0 + q;
        u16* prow = pw + q * 64;
#pragma unroll
        for (int n = 0; n < 4; n++) {
          float p = exp2f(sa[n][i] * SC2_);
          if (diag) p = ((kv0 + n * 16 + lr) > r) ? 0.f : p;
          l_i[i] += p;
          int chn = ((n * 2 + (lr >> 3)) ^ (q & 7));
          prow[chn * 8 + (lr & 7)] = f2bf(p);
        }
      }
      asm volatile("s_waitcnt lgkmcnt(0)" ::: "memory");

      bfx8 pa[2];
#pragma unroll
      for (int ks = 0; ks < 2; ks++) {
        int cp = (4 * ks + lg) ^ (lr & 7);
        pa[ks] = *(const bfx8*)(pw + lr * 64 + cp * 8);
      }
      __builtin_amdgcn_s_setprio(1);
#pragma unroll
      for (int nf = 0; nf < 8; nf++) {
        int d = nf * 16 + lr;
        const u16* vrow = Vd + d * 64;
#pragma unroll
        for (int ks = 0; ks < 2; ks++) {
          int cv = (4 * ks + lg) ^ (d & 7);
          bfx8 vf = *(const bfx8*)(vrow + cv * 8);
          o[nf] = __builtin_amdgcn_mfma_f32_16x16x32_bf16(pa[ks], vf, o[nf], 0, 0, 0);
        }
      }
      __builtin_amdgcn_s_setprio(0);
    }
    __builtin_amdgcn_s_barrier();
    cur ^= 1;
  }

  float inv[4];
#pragma unroll
  for (int i = 0; i < 4; i++) {
    float l = l_i[i];
    l += __shfl_xor(l, 1);
    l += __shfl_xor(l, 2);
    l += __shfl_xor(l, 4);
    l += __shfl_xor(l, 8);
    inv[i] = 1.0f / l;
  }
  u16* ob = Og + ((size_t)(b * T_ + qr0)) * DM + h * HD;
#pragma unroll
  for (int nf = 0; nf < 8; nf++)
#pragma unroll
    for (int i = 0; i < 4; i++)
      ob[(size_t)(4 * lg + i) * DM + nf * 16 + lr] = f2bf(o[nf][i] * inv[i]);
}

// ---------------- launch ----------------
extern "C" void kernel_launch(void* const* d_in, const int* in_sizes, int n_in,
                              void* d_out, int out_size, void* d_ws, size_t ws_size,
                              hipStream_t stream) {
  const float* x = (const float*)d_in[0];
  const float* cosp = (const float*)d_in[2];
  const float* sinp = (const float*)d_in[3];
  const float* Wq = (const float*)d_in[4];
  const float* Wk = (const float*)d_in[5];
  const float* Wv = (const float*)d_in[6];
  const float* Wo = (const float*)d_in[7];
  const float* bo = (const float*)d_in[8];
  const float* gq = (const float*)d_in[9];
  const float* gk = (const float*)d_in[10];

  char* ws = (char*)d_ws;
  u16* xbf  = (u16*)(ws + 0);           // 16 MB
  u16* wqkv = (u16*)(ws + 16777216);    // 16 MB
  u16* wo   = (u16*)(ws + 33554432);    // 8 MB
  u16* qkv  = (u16*)(ws + 41943040);    // 32 MB
  u16* qb   = (u16*)(ws + 75497472);    // 16 MB
  u16* kb   = (u16*)(ws + 92274688);    // 8 MB
  u16* vt   = (u16*)(ws + 100663296);   // 8 MB
  u16* ab   = (u16*)(ws + 109051904);   // 16 MB
  float* out = (float*)d_out;

  k_cvt<<<8192, 256, 0, stream>>>(x, xbf, 8388608);
  k_cvt<<<4096, 256, 0, stream>>>(Wq, wqkv, 4194304);
  k_cvt<<<2048, 256, 0, stream>>>(Wk, wqkv + 4194304, 2097152);
  k_cvt<<<2048, 256, 0, stream>>>(Wv, wqkv + 6291456, 2097152);
  k_cvt<<<4096, 256, 0, stream>>>(Wo, wo, 4194304);

  k_gemm256<<<256, 512, 0, stream>>>(xbf, wqkv, qkv, 4096, 4096, 2048);
  k_qkpost<<<1536, 256, 0, stream>>>(qkv, cosp, sinp, gq, gk, qb, kb);
  k_vtr<<<512, 256, 0, stream>>>(qkv, vt);
  k_attn<<<512, 512, 0, stream>>>(qb, kb, vt, ab);
  k_gemmo<<<512, 256, 0, stream>>>(ab, wo, out, bo, 4096, 2048, 2048);
}

// Round 11
// 236.252 us; speedup vs baseline: 1.1309x; 1.0299x over previous
//
#include <hip/hip_runtime.h>
#include <stdint.h>

#define B_ 2
#define T_ 2048
#define DM 2048
#define NH 16
#define NKV 8
#define HD 128
#define NQKV 4096
#define SC2_ 0.12753102765f  // (1/sqrt(128)) * log2(e)

typedef float fx4 __attribute__((ext_vector_type(4)));
typedef __bf16 bfx8 __attribute__((ext_vector_type(8)));
typedef unsigned short u16;
typedef unsigned int u32;

typedef __attribute__((address_space(1))) const void gas_t;
typedef __attribute__((address_space(3))) void las_t;

__device__ __forceinline__ u16 f2bf(float f) {
  u32 u = __float_as_uint(f);
  u = (u + 0x7fffu + ((u >> 16) & 1u)) >> 16;
  return (u16)u;
}

// HW packed f32->bf16 pair (T12): lo -> bits[15:0], hi -> bits[31:16]
__device__ __forceinline__ u32 cvtpk(float lo, float hi) {
  u32 r;
  asm("v_cvt_pk_bf16_f32 %0, %1, %2" : "=v"(r) : "v"(lo), "v"(hi));
  return r;
}

// async global->LDS, 16B per lane; lds arg must be wave-uniform base + lane*16
__device__ __forceinline__ void stage16(const void* g, void* l) {
  __builtin_amdgcn_global_load_lds((gas_t*)(uintptr_t)g, (las_t*)(uintptr_t)l,
                                   16, 0, 0);
}

// ---------------- fp32 -> bf16 convert ----------------
__global__ void k_cvt(const float* __restrict__ in, u16* __restrict__ out, int n) {
  int i = (blockIdx.x * blockDim.x + threadIdx.x) * 4;
  if (i + 3 < n) {
    float4 v = *(const float4*)(in + i);
    u32 w0 = (u32)f2bf(v.x) | ((u32)f2bf(v.y) << 16);
    u32 w1 = (u32)f2bf(v.z) | ((u32)f2bf(v.w) << 16);
    *(uint2*)(out + i) = make_uint2(w0, w1);
  }
}

// ======== 256x256 8-phase GEMM (T2+T3+T4+T5): C[M][N] = A[M][K] B[N][K]^T ========
// Epilogue-race fix: end-of-tile waits vmcnt(0) when no t+2 stage was issued.
__global__ __launch_bounds__(512, 2) void k_gemm256(const u16* __restrict__ A,
                                                    const u16* __restrict__ Bm,
                                                    u16* __restrict__ C,
                                                    int M, int N, int K) {
  __shared__ __align__(16) u16 As[2][2][256 * 32];
  __shared__ __align__(16) u16 Bs[2][2][256 * 32];
  const int nbn = N >> 8;
  const int bm = blockIdx.x / nbn, bn = blockIdx.x % nbn;
  const int tid = threadIdx.x;
  const int w = tid >> 6, lane = tid & 63;
  const int wm = w >> 2, wn = w & 3;
  const int lr = lane & 15, lg = lane >> 4;
  const int cw = (lg ^ ((lr >> 1) & 3)) * 8;
  const u16* Ab = A + (size_t)bm * 256 * K;
  const u16* Bb = Bm + (size_t)bn * 256 * K;
  const int NT = K >> 6;

  auto stage = [&](const u16* gb, u16* region, int tile, int kh) {
#pragma unroll
    for (int i = 0; i < 2; i++) {
      int q = tid + i * 512;
      int row = q >> 2, ch = q & 3;
      int sc = ch ^ ((row >> 1) & 3);
      stage16(gb + (size_t)row * K + tile * 64 + kh * 32 + sc * 8, region + q * 8);
    }
  };

  fx4 acc[8][4];
  const fx4 zero4 = {0.f, 0.f, 0.f, 0.f};
#pragma unroll
  for (int m = 0; m < 8; m++)
#pragma unroll
    for (int n = 0; n < 4; n++) acc[m][n] = zero4;

  stage(Ab, &As[0][0][0], 0, 0);
  stage(Bb, &Bs[0][0][0], 0, 0);
  stage(Ab, &As[0][1][0], 0, 1);
  stage(Bb, &Bs[0][1][0], 0, 1);
  stage(Ab, &As[1][0][0], 1, 0);
  stage(Bb, &Bs[1][0][0], 1, 0);
  asm volatile("s_waitcnt vmcnt(4)" ::: "memory");
  __builtin_amdgcn_s_barrier();

  const int arow = (wm * 128 + lr) * 32;
  const int brow = (wn * 64 + lr) * 32;
  bfx8 af[4], bf[4];

#pragma unroll 1
  for (int t = 0; t < NT; t++) {
    const u16* A0 = &As[t & 1][0][0];
    const u16* A1 = &As[t & 1][1][0];
    const u16* B0 = &Bs[t & 1][0][0];
    const u16* B1 = &Bs[t & 1][1][0];
    const int p1 = (t + 1) & 1, p2 = t & 1;

#pragma unroll
    for (int mi = 0; mi < 4; mi++) af[mi] = *(const bfx8*)(A0 + arow + mi * 512 + cw);
#pragma unroll
    for (int n = 0; n < 4; n++) bf[n] = *(const bfx8*)(B0 + brow + n * 512 + cw);
    if (t + 1 < NT) stage(Ab, &As[p1][1][0], t + 1, 1);
    __builtin_amdgcn_s_barrier();
    asm volatile("s_waitcnt lgkmcnt(0)" ::: "memory");
    __builtin_amdgcn_sched_barrier(0);
    __builtin_amdgcn_s_setprio(1);
#pragma unroll
    for (int mi = 0; mi < 4; mi++)
#pragma unroll
      for (int n = 0; n < 4; n++)
        acc[mi][n] = __builtin_amdgcn_mfma_f32_16x16x32_bf16(af[mi], bf[n], acc[mi][n], 0, 0, 0);
    __builtin_amdgcn_s_setprio(0);
    __builtin_amdgcn_s_barrier();

#pragma unroll
    for (int mi = 0; mi < 4; mi++)
      af[mi] = *(const bfx8*)(A0 + arow + 2048 + mi * 512 + cw);
    if (t + 1 < NT) stage(Bb, &Bs[p1][1][0], t + 1, 1);
    __builtin_amdgcn_s_barrier();
    asm volatile("s_waitcnt lgkmcnt(0)" ::: "memory");
    __builtin_amdgcn_sched_barrier(0);
    __builtin_amdgcn_s_setprio(1);
#pragma unroll
    for (int mi = 0; mi < 4; mi++)
#pragma unroll
      for (int n = 0; n < 4; n++)
        acc[4 + mi][n] = __builtin_amdgcn_mfma_f32_16x16x32_bf16(af[mi], bf[n], acc[4 + mi][n], 0, 0, 0);
    __builtin_amdgcn_s_setprio(0);
    __builtin_amdgcn_s_barrier();

#pragma unroll
    for (int mi = 0; mi < 4; mi++) af[mi] = *(const bfx8*)(A1 + arow + mi * 512 + cw);
#pragma unroll
    for (int n = 0; n < 4; n++) bf[n] = *(const bfx8*)(B1 + brow + n * 512 + cw);
    if (t + 2 < NT) stage(Ab, &As[p2][0][0], t + 2, 0);
    __builtin_amdgcn_s_barrier();
    asm volatile("s_waitcnt lgkmcnt(0)" ::: "memory");
    __builtin_amdgcn_sched_barrier(0);
    __builtin_amdgcn_s_setprio(1);
#pragma unroll
    for (int mi = 0; mi < 4; mi++)
#pragma unroll
      for (int n = 0; n < 4; n++)
        acc[mi][n] = __builtin_amdgcn_mfma_f32_16x16x32_bf16(af[mi], bf[n], acc[mi][n], 0, 0, 0);
    __builtin_amdgcn_s_setprio(0);
    __builtin_amdgcn_s_barrier();

#pragma unroll
    for (int mi = 0; mi < 4; mi++)
      af[mi] = *(const bfx8*)(A1 + arow + 2048 + mi * 512 + cw);
    if (t + 2 < NT) stage(Bb, &Bs[p2][0][0], t + 2, 0);
    __builtin_amdgcn_s_barrier();
    asm volatile("s_waitcnt lgkmcnt(0)" ::: "memory");
    __builtin_amdgcn_sched_barrier(0);
    __builtin_amdgcn_s_setprio(1);
#pragma unroll
    for (int mi = 0; mi < 4; mi++)
#pragma unroll
      for (int n = 0; n < 4; n++)
        acc[4 + mi][n] = __builtin_amdgcn_mfma_f32_16x16x32_bf16(af[mi], bf[n], acc[4 + mi][n], 0, 0, 0);
    __builtin_amdgcn_s_setprio(0);
    if (t + 2 < NT) {
      asm volatile("s_waitcnt vmcnt(4)" ::: "memory");
    } else {
      asm volatile("s_waitcnt vmcnt(0)" ::: "memory");
    }
    __builtin_amdgcn_s_barrier();
  }

  const int r0 = bm * 256 + wm * 128, c0 = bn * 256 + wn * 64;
#pragma unroll
  for (int m = 0; m < 8; m++) {
#pragma unroll
    for (int n = 0; n < 4; n++) {
      int c = c0 + n * 16 + lr;
#pragma unroll
      for (int i = 0; i < 4; i++)
        C[(size_t)(r0 + m * 16 + lg * 4 + i) * N + c] = f2bf(acc[m][n][i]);
    }
  }
}

// ======== 128x128 8-phase GEMM, f32+bias out (out-proj), race-fixed ========
__global__ __launch_bounds__(256, 2) void k_gemmo(const u16* __restrict__ A,
                                                  const u16* __restrict__ Bm,
                                                  float* __restrict__ C,
                                                  const float* __restrict__ bias,
                                                  int M, int N, int K) {
  __shared__ __align__(16) u16 As[2][2][128 * 32];
  __shared__ __align__(16) u16 Bs[2][2][128 * 32];
  const int nbn = N >> 7;
  const int bm = blockIdx.x / nbn, bn = blockIdx.x % nbn;
  const int tid = threadIdx.x;
  const int w = tid >> 6, lane = tid & 63;
  const int wm = w >> 1, wn = w & 1;
  const int lr = lane & 15, lg = lane >> 4;
  const int cw = (lg ^ ((lr >> 1) & 3)) * 8;
  const u16* Ab = A + (size_t)bm * 128 * K;
  const u16* Bb = Bm + (size_t)bn * 128 * K;
  const int NT = K >> 6;

  auto stage = [&](const u16* gb, u16* region, int tile, int kh) {
#pragma unroll
    for (int i = 0; i < 2; i++) {
      int q = tid + i * 256;
      int row = q >> 2, ch = q & 3;
      int sc = ch ^ ((row >> 1) & 3);
      stage16(gb + (size_t)row * K + tile * 64 + kh * 32 + sc * 8, region + q * 8);
    }
  };

  fx4 acc[4][4];
  const fx4 zero4 = {0.f, 0.f, 0.f, 0.f};
#pragma unroll
  for (int m = 0; m < 4; m++)
#pragma unroll
    for (int n = 0; n < 4; n++) acc[m][n] = zero4;

  stage(Ab, &As[0][0][0], 0, 0);
  stage(Bb, &Bs[0][0][0], 0, 0);
  stage(Ab, &As[0][1][0], 0, 1);
  stage(Bb, &Bs[0][1][0], 0, 1);
  stage(Ab, &As[1][0][0], 1, 0);
  stage(Bb, &Bs[1][0][0], 1, 0);
  asm volatile("s_waitcnt vmcnt(4)" ::: "memory");
  __builtin_amdgcn_s_barrier();

  const int arow = (wm * 64 + lr) * 32;
  const int brow = (wn * 64 + lr) * 32;
  bfx8 af[2], bf[4];

#pragma unroll 1
  for (int t = 0; t < NT; t++) {
    const u16* A0 = &As[t & 1][0][0];
    const u16* A1 = &As[t & 1][1][0];
    const u16* B0 = &Bs[t & 1][0][0];
    const u16* B1 = &Bs[t & 1][1][0];
    const int p1 = (t + 1) & 1, p2 = t & 1;

#pragma unroll
    for (int mi = 0; mi < 2; mi++) af[mi] = *(const bfx8*)(A0 + arow + mi * 512 + cw);
#pragma unroll
    for (int n = 0; n < 4; n++) bf[n] = *(const bfx8*)(B0 + brow + n * 512 + cw);
    if (t + 1 < NT) stage(Ab, &As[p1][1][0], t + 1, 1);
    __builtin_amdgcn_s_barrier();
    asm volatile("s_waitcnt lgkmcnt(0)" ::: "memory");
    __builtin_amdgcn_sched_barrier(0);
    __builtin_amdgcn_s_setprio(1);
#pragma unroll
    for (int mi = 0; mi < 2; mi++)
#pragma unroll
      for (int n = 0; n < 4; n++)
        acc[mi][n] = __builtin_amdgcn_mfma_f32_16x16x32_bf16(af[mi], bf[n], acc[mi][n], 0, 0, 0);
    __builtin_amdgcn_s_setprio(0);
    __builtin_amdgcn_s_barrier();

#pragma unroll
    for (int mi = 0; mi < 2; mi++)
      af[mi] = *(const bfx8*)(A0 + arow + 1024 + mi * 512 + cw);
    if (t + 1 < NT) stage(Bb, &Bs[p1][1][0], t + 1, 1);
    __builtin_amdgcn_s_barrier();
    asm volatile("s_waitcnt lgkmcnt(0)" ::: "memory");
    __builtin_amdgcn_sched_barrier(0);
    __builtin_amdgcn_s_setprio(1);
#pragma unroll
    for (int mi = 0; mi < 2; mi++)
#pragma unroll
      for (int n = 0; n < 4; n++)
        acc[2 + mi][n] = __builtin_amdgcn_mfma_f32_16x16x32_bf16(af[mi], bf[n], acc[2 + mi][n], 0, 0, 0);
    __builtin_amdgcn_s_setprio(0);
    __builtin_amdgcn_s_barrier();

#pragma unroll
    for (int mi = 0; mi < 2; mi++) af[mi] = *(const bfx8*)(A1 + arow + mi * 512 + cw);
#pragma unroll
    for (int n = 0; n < 4; n++) bf[n] = *(const bfx8*)(B1 + brow + n * 512 + cw);
    if (t + 2 < NT) stage(Ab, &As[p2][0][0], t + 2, 0);
    __builtin_amdgcn_s_barrier();
    asm volatile("s_waitcnt lgkmcnt(0)" ::: "memory");
    __builtin_amdgcn_sched_barrier(0);
    __builtin_amdgcn_s_setprio(1);
#pragma unroll
    for (int mi = 0; mi < 2; mi++)
#pragma unroll
      for (int n = 0; n < 4; n++)
        acc[mi][n] = __builtin_amdgcn_mfma_f32_16x16x32_bf16(af[mi], bf[n], acc[mi][n], 0, 0, 0);
    __builtin_amdgcn_s_setprio(0);
    __builtin_amdgcn_s_barrier();

#pragma unroll
    for (int mi = 0; mi < 2; mi++)
      af[mi] = *(const bfx8*)(A1 + arow + 1024 + mi * 512 + cw);
    if (t + 2 < NT) stage(Bb, &Bs[p2][0][0], t + 2, 0);
    __builtin_amdgcn_s_barrier();
    asm volatile("s_waitcnt lgkmcnt(0)" ::: "memory");
    __builtin_amdgcn_sched_barrier(0);
    __builtin_amdgcn_s_setprio(1);
#pragma unroll
    for (int mi = 0; mi < 2; mi++)
#pragma unroll
      for (int n = 0; n < 4; n++)
        acc[2 + mi][n] = __builtin_amdgcn_mfma_f32_16x16x32_bf16(af[mi], bf[n], acc[2 + mi][n], 0, 0, 0);
    __builtin_amdgcn_s_setprio(0);
    if (t + 2 < NT) {
      asm volatile("s_waitcnt vmcnt(4)" ::: "memory");
    } else {
      asm volatile("s_waitcnt vmcnt(0)" ::: "memory");
    }
    __builtin_amdgcn_s_barrier();
  }

  const int r0 = bm * 128 + wm * 64, c0 = bn * 128 + wn * 64;
#pragma unroll
  for (int m = 0; m < 4; m++) {
#pragma unroll
    for (int n = 0; n < 4; n++) {
      int c = c0 + n * 16 + lr;
#pragma unroll
      for (int i = 0; i < 4; i++)
        C[(size_t)(r0 + m * 16 + lg * 4 + i) * N + c] = acc[m][n][i] + bias[c];
    }
  }
}

// ---------------- Q/K epilogue: rmsnorm + rope, relayout ----------------
__global__ __launch_bounds__(256) void k_qkpost(const u16* __restrict__ qkv,
                                                const float* __restrict__ cosp,
                                                const float* __restrict__ sinp,
                                                const float* __restrict__ gq,
                                                const float* __restrict__ gk,
                                                u16* __restrict__ Qo,
                                                u16* __restrict__ Ko) {
  int bi = blockIdx.x;
  int hh = bi % 24;
  int t64 = (bi / 24) % 32;
  int b = bi / 768;
  int tid = threadIdx.x;
  int j = tid >> 2, p = tid & 3;
  int t = t64 * 64 + j;
  bool isq = hh < 16;
  int colbase = isq ? hh * 128 : 2048 + (hh - 16) * 128;
  const u16* src = qkv + ((size_t)(b * T_ + t)) * NQKV + colbase + p * 32;

  float xv[32];
#pragma unroll
  for (int c = 0; c < 4; c++) {
    uint4 raw = *(const uint4*)(src + c * 8);
    u32 wd[4] = {raw.x, raw.y, raw.z, raw.w};
#pragma unroll
    for (int q2 = 0; q2 < 4; q2++) {
      xv[c * 8 + q2 * 2 + 0] = __uint_as_float(wd[q2] << 16);
      xv[c * 8 + q2 * 2 + 1] = __uint_as_float(wd[q2] & 0xffff0000u);
    }
  }
  float ss = 0.f;
#pragma unroll
  for (int i = 0; i < 32; i++) ss += xv[i] * xv[i];
  ss += __shfl_xor(ss, 1);
  ss += __shfl_xor(ss, 2);
  float rinv = rsqrtf(ss * (1.0f / 128.0f) + 1e-6f);
  const float* g = isq ? gq : gk;
  const float* cr = cosp + (size_t)t * 128 + p * 32;
  const float* sr = sinp + (size_t)t * 128 + p * 32;

  float ov[32];
#pragma unroll
  for (int i = 0; i < 32; i++) {
    float y = xv[i] * rinv * g[p * 32 + i];
    float oth = __shfl_xor(y, 2);
    float rot = (p < 2) ? -oth : oth;
    ov[i] = y * cr[i] + rot * sr[i];
  }

  uint4 pk[4];
#pragma unroll
  for (int c = 0; c < 4; c++) {
    u32 wd[4];
#pragma unroll
    for (int q2 = 0; q2 < 4; q2++)
      wd[q2] = (u32)f2bf(ov[c * 8 + q2 * 2]) | ((u32)f2bf(ov[c * 8 + q2 * 2 + 1]) << 16);
    pk[c] = make_uint4(wd[0], wd[1], wd[2], wd[3]);
  }

  if (isq) {
    u16* dst = Qo + (((size_t)(b * NH + hh)) * T_ + t) * HD + p * 32;
#pragma unroll
    for (int c = 0; c < 4; c++) *(uint4*)(dst + c * 8) = pk[c];
  } else {
    int hk = hh - 16;
    u16* dstrow = Ko + (((size_t)(b * NKV + hk)) * T_ + t) * HD;
#pragma unroll
    for (int c = 0; c < 4; c++) {
      int C = p * 4 + c;
      int Cs = C ^ (t & 7);  // XOR swizzle (16 chunks/row), matches attn read
      *(uint4*)(dstrow + Cs * 8) = pk[c];
    }
  }
}

// ---------------- V transpose: qkv[...,3072+] -> vt[b][hkv][d][t] ----------------
__global__ __launch_bounds__(256) void k_vtr(const u16* __restrict__ qkv,
                                             u16* __restrict__ vt) {
  __shared__ __align__(16) u16 sm[128 * 64];
  int bi = blockIdx.x;
  int hv = bi & 7;
  int t64 = (bi >> 3) & 31;
  int b = bi >> 8;
  int tid = threadIdx.x;
#pragma unroll
  for (int it = 0; it < 4; it++) {
    int idx = tid + it * 256;
    int tok = idx >> 4, c = idx & 15;
    uint4 raw = *(const uint4*)(qkv + ((size_t)(b * T_ + t64 * 64 + tok)) * NQKV +
                                3072 + hv * 128 + c * 8);
    u32 wd[4] = {raw.x, raw.y, raw.z, raw.w};
#pragma unroll
    for (int q2 = 0; q2 < 4; q2++) {
      sm[(c * 8 + q2 * 2 + 0) * 64 + tok] = (u16)(wd[q2] & 0xffffu);
      sm[(c * 8 + q2 * 2 + 1) * 64 + tok] = (u16)(wd[q2] >> 16);
    }
  }
  __syncthreads();
  int d = tid >> 1, half = tid & 1;
  size_t rowb = (((size_t)(b * NKV + hv)) * HD + d) * T_ + t64 * 64;
#pragma unroll
  for (int c = 0; c < 4; c++) {
    int cg = half * 4 + c;
    int cs = cg ^ (d & 7);
    u32 wd[4];
#pragma unroll
    for (int q2 = 0; q2 < 4; q2++) {
      u32 lo = sm[d * 64 + half * 32 + c * 8 + 2 * q2];
      u32 hi = sm[d * 64 + half * 32 + c * 8 + 2 * q2 + 1];
      wd[q2] = lo | (hi << 16);
    }
    *(uint4*)(vt + rowb + cs * 8) = make_uint4(wd[0], wd[1], wd[2], wd[3]);
  }
}

// ---------------- flash attention v5: r5 structure + transposed-S cvt_pk P-store ----
// grid = B*NH*16 = 512 blocks, 512 thr (8 waves). Waves 0-3: q-tile z,
// waves 4-7: q-tile 31-z, one shared K/V staging stream (prefix property).
// QK^T computed SWAPPED (mfma(K,Q) -> S^T): lane holds 4 consecutive kv for
// q=lr -> P-store = cvt_pk pairs + ds_write_b64 (vs 16 f2bf + 16 b16 writes).
// No-max softmax (rmsnorm-bounded scores), counted vmcnt, raw barriers.
__global__ __launch_bounds__(512, 4) void k_attn(const u16* __restrict__ Qg,
                                                 const u16* __restrict__ Kg,
                                                 const u16* __restrict__ Vg,
                                                 u16* __restrict__ Og) {
  __shared__ __align__(16) u16 Ks[2][64 * 128];
  __shared__ __align__(16) u16 Vs[2][128 * 64];
  __shared__ __align__(16) u16 Ps[8][16 * 64];
  const int bi = blockIdx.x;
  const int zr = bi & 15, h = (bi >> 4) & 15, b = bi >> 8;
  const int z = b ? (15 - zr) : zr;
  const int hkv = h >> 1;
  const int tid = threadIdx.x, w = tid >> 6, lane = tid & 63;
  const int lr = lane & 15, lg = lane >> 4;
  const int zt = (w < 4) ? z : (31 - z);
  const int qr0 = zt * 64 + (w & 3) * 16;
  const int qrow = qr0 + lr;  // q row owned by this lane (S^T column)
  const int nch = 32 - z;
  const int myl = zt + 1;

  const u16* kb = Kg + ((size_t)(b * NKV + hkv)) * T_ * HD;
  const u16* vb = Vg + ((size_t)(b * NKV + hkv)) * HD * T_;
  u16* pw = &Ps[w][0];
  const fx4 zero4 = {0.f, 0.f, 0.f, 0.f};

  auto stageKV = [&](int buf, int kv0) {
    u16* Kd = &Ks[buf][0];
    u16* Vd = &Vs[buf][0];
#pragma unroll
    for (int it = 0; it < 2; it++) {
      int r = it * 32 + (tid >> 4);
      stage16(kb + (size_t)(kv0 + r) * HD + (tid & 15) * 8, Kd + it * 4096 + tid * 8);
      int d = it * 64 + (tid >> 3);
      stage16(vb + (size_t)d * T_ + kv0 + (tid & 7) * 8, Vd + it * 4096 + tid * 8);
    }
  };

  const u16* qbase = Qg + (((size_t)(b * NH + h)) * T_ + qrow) * HD;
  bfx8 qf[4];
#pragma unroll
  for (int kk = 0; kk < 4; kk++) qf[kk] = *(const bfx8*)(qbase + kk * 32 + lg * 8);

  fx4 o[8];
#pragma unroll
  for (int nf = 0; nf < 8; nf++) o[nf] = zero4;
  float l_i = 0.f;  // partial softmax denom for q = qrow (this lane's column)

  stageKV(0, 0);
  asm volatile("s_waitcnt vmcnt(0)" ::: "memory");
  __builtin_amdgcn_s_barrier();
  int cur = 0;

#pragma unroll 1
  for (int ch = 0; ch < nch; ch++) {
    if (ch + 1 < nch) {
      stageKV(cur ^ 1, (ch + 1) * 64);
      asm volatile("s_waitcnt vmcnt(4)" ::: "memory");
    } else {
      asm volatile("s_waitcnt vmcnt(0)" ::: "memory");
    }
    __builtin_amdgcn_s_barrier();

    if (ch < myl) {
      const u16* Kd = &Ks[cur][0];
      const u16* Vd = &Vs[cur][0];
      const int kv0 = ch * 64;
      const bool diag = (ch == zt);

      // ---- S^T = mfma(K, Q): lane holds kv = n*16 + 4*lg + i, col q = lr ----
      fx4 sa[4];
#pragma unroll
      for (int n = 0; n < 4; n++) sa[n] = zero4;
      __builtin_amdgcn_s_setprio(1);
#pragma unroll
      for (int n = 0; n < 4; n++) {
        const int kvl = n * 16 + lr;
        const u16* krow = Kd + kvl * 128;
#pragma unroll
        for (int kk = 0; kk < 4; kk++) {
          int cs = (kk * 4 + lg) ^ (kvl & 7);
          bfx8 kf = *(const bfx8*)(krow + cs * 8);
          sa[n] = __builtin_amdgcn_mfma_f32_16x16x32_bf16(kf, qf[kk], sa[n], 0, 0, 0);
        }
      }
      __builtin_amdgcn_s_setprio(0);

      // ---- no-max softmax + packed P-store (4 consecutive kv per lane) ----
#pragma unroll
      for (int n = 0; n < 4; n++) {
        float p0 = exp2f(sa[n][0] * SC2_);
        float p1 = exp2f(sa[n][1] * SC2_);
        float p2 = exp2f(sa[n][2] * SC2_);
        float p3 = exp2f(sa[n][3] * SC2_);
        if (diag) {
          int kvg = kv0 + n * 16 + 4 * lg;  // kv of element 0
          p0 = (kvg + 0 > qrow) ? 0.f : p0;
          p1 = (kvg + 1 > qrow) ? 0.f : p1;
          p2 = (kvg + 2 > qrow) ? 0.f : p2;
          p3 = (kvg + 3 > qrow) ? 0.f : p3;
        }
        l_i += (p0 + p1) + (p2 + p3);
        u32 w0 = cvtpk(p0, p1);
        u32 w1 = cvtpk(p2, p3);
        int c = 2 * n + (lg >> 1);
        int cs = c ^ (lr & 7);
        *(uint2*)(pw + lr * 64 + cs * 8 + 4 * (lg & 1)) = make_uint2(w0, w1);
      }
      asm volatile("s_waitcnt lgkmcnt(0)" ::: "memory");
      __builtin_amdgcn_sched_barrier(0);

      // ---- O += P V (P read back as A-fragments, swizzle matches write) ----
      bfx8 pa[2];
#pragma unroll
      for (int ks = 0; ks < 2; ks++) {
        int cp = (4 * ks + lg) ^ (lr & 7);
        pa[ks] = *(const bfx8*)(pw + lr * 64 + cp * 8);
      }
      __builtin_amdgcn_s_setprio(1);
#pragma unroll
      for (int nf = 0; nf < 8; nf++) {
        int d = nf * 16 + lr;
        const u16* vrow = Vd + d * 64;
#pragma unroll
        for (int ks = 0; ks < 2; ks++) {
          int cv = (4 * ks + lg) ^ (d & 7);
          bfx8 vf = *(const bfx8*)(vrow + cv * 8);
          o[nf] = __builtin_amdgcn_mfma_f32_16x16x32_bf16(pa[ks], vf, o[nf], 0, 0, 0);
        }
      }
      __builtin_amdgcn_s_setprio(0);
    }
    __builtin_amdgcn_s_barrier();
    cur ^= 1;
  }

  // ---- finalize: lane's l is for q=lr; combine the 4 lanes sharing lr ----
  float lt = l_i + __shfl_xor(l_i, 16);
  lt += __shfl_xor(lt, 32);
  float inv[4];
#pragma unroll
  for (int i = 0; i < 4; i++) inv[i] = 1.0f / __shfl(lt, 4 * lg + i);
  u16* ob = Og + ((size_t)(b * T_ + qr0)) * DM + h * HD;
#pragma unroll
  for (int nf = 0; nf < 8; nf++)
#pragma unroll
    for (int i = 0; i < 4; i++)
      ob[(size_t)(4 * lg + i) * DM + nf * 16 + lr] = f2bf(o[nf][i] * inv[i]);
}

// ---------------- launch ----------------
extern "C" void kernel_launch(void* const* d_in, const int* in_sizes, int n_in,
                              void* d_out, int out_size, void* d_ws, size_t ws_size,
                              hipStream_t stream) {
  const float* x = (const float*)d_in[0];
  const float* cosp = (const float*)d_in[2];
  const float* sinp = (const float*)d_in[3];
  const float* Wq = (const float*)d_in[4];
  const float* Wk = (const float*)d_in[5];
  const float* Wv = (const float*)d_in[6];
  const float* Wo = (const float*)d_in[7];
  const float* bo = (const float*)d_in[8];
  const float* gq = (const float*)d_in[9];
  const float* gk = (const float*)d_in[10];

  char* ws = (char*)d_ws;
  u16* xbf  = (u16*)(ws + 0);           // 16 MB
  u16* wqkv = (u16*)(ws + 16777216);    // 16 MB
  u16* wo   = (u16*)(ws + 33554432);    // 8 MB
  u16* qkv  = (u16*)(ws + 41943040);    // 32 MB
  u16* qb   = (u16*)(ws + 75497472);    // 16 MB
  u16* kb   = (u16*)(ws + 92274688);    // 8 MB
  u16* vt   = (u16*)(ws + 100663296);   // 8 MB
  u16* ab   = (u16*)(ws + 109051904);   // 16 MB
  float* out = (float*)d_out;

  k_cvt<<<8192, 256, 0, stream>>>(x, xbf, 8388608);
  k_cvt<<<4096, 256, 0, stream>>>(Wq, wqkv, 4194304);
  k_cvt<<<2048, 256, 0, stream>>>(Wk, wqkv + 4194304, 2097152);
  k_cvt<<<2048, 256, 0, stream>>>(Wv, wqkv + 6291456, 2097152);
  k_cvt<<<4096, 256, 0, stream>>>(Wo, wo, 4194304);

  k_gemm256<<<256, 512, 0, stream>>>(xbf, wqkv, qkv, 4096, 4096, 2048);
  k_qkpost<<<1536, 256, 0, stream>>>(qkv, cosp, sinp, gq, gk, qb, kb);
  k_vtr<<<512, 256, 0, stream>>>(qkv, vt);
  k_attn<<<512, 512, 0, stream>>>(qb, kb, vt, ab);
  k_gemmo<<<512, 256, 0, stream>>>(ab, wo, out, bo, 4096, 2048, 2048);
}

// Round 12
// 230.107 us; speedup vs baseline: 1.1611x; 1.0267x over previous
//
#include <hip/hip_runtime.h>
#include <stdint.h>

#define B_ 2
#define T_ 2048
#define DM 2048
#define NH 16
#define NKV 8
#define HD 128
#define NQKV 4096
#define SC2_ 0.12753102765f  // (1/sqrt(128)) * log2(e)

typedef float fx4 __attribute__((ext_vector_type(4)));
typedef __bf16 bfx8 __attribute__((ext_vector_type(8)));
typedef unsigned short u16;
typedef unsigned int u32;

typedef __attribute__((address_space(1))) const void gas_t;
typedef __attribute__((address_space(3))) void las_t;

__device__ __forceinline__ u16 f2bf(float f) {
  u32 u = __float_as_uint(f);
  u = (u + 0x7fffu + ((u >> 16) & 1u)) >> 16;
  return (u16)u;
}

// HW packed f32->bf16 pair (T12): lo -> bits[15:0], hi -> bits[31:16]
__device__ __forceinline__ u32 cvtpk(float lo, float hi) {
  u32 r;
  asm("v_cvt_pk_bf16_f32 %0, %1, %2" : "=v"(r) : "v"(lo), "v"(hi));
  return r;
}

// async global->LDS, 16B per lane; lds arg must be wave-uniform base + lane*16
__device__ __forceinline__ void stage16(const void* g, void* l) {
  __builtin_amdgcn_global_load_lds((gas_t*)(uintptr_t)g, (las_t*)(uintptr_t)l,
                                   16, 0, 0);
}

// ---------------- fp32 -> bf16 convert (x) ----------------
__global__ void k_cvt(const float* __restrict__ in, u16* __restrict__ out, int n) {
  int i = (blockIdx.x * blockDim.x + threadIdx.x) * 4;
  if (i + 3 < n) {
    float4 v = *(const float4*)(in + i);
    u32 w0 = (u32)f2bf(v.x) | ((u32)f2bf(v.y) << 16);
    u32 w1 = (u32)f2bf(v.z) | ((u32)f2bf(v.w) << 16);
    *(uint2*)(out + i) = make_uint2(w0, w1);
  }
}

// ---------------- fused weight convert: Wq|Wk|Wv -> wqkv, Wo -> wo (contiguous dst) --
__global__ void k_cvtw(const float* __restrict__ wq, const float* __restrict__ wk,
                       const float* __restrict__ wv, const float* __restrict__ wo,
                       u16* __restrict__ out) {
  int i = (blockIdx.x * blockDim.x + threadIdx.x) * 4;  // 0..12582912
  const float* src;
  int off;
  if (i < 4194304) { src = wq; off = i; }
  else if (i < 6291456) { src = wk; off = i - 4194304; }
  else if (i < 8388608) { src = wv; off = i - 6291456; }
  else { src = wo; off = i - 8388608; }
  float4 v = *(const float4*)(src + off);
  u32 w0 = (u32)f2bf(v.x) | ((u32)f2bf(v.y) << 16);
  u32 w1 = (u32)f2bf(v.z) | ((u32)f2bf(v.w) << 16);
  *(uint2*)(out + i) = make_uint2(w0, w1);
}

// ======== 256x256 GEMM, 2 merged phases/K-tile: C[M][N] = A[M][K] B[N][K]^T ========
// Per tile: phase A {read kh0 frags (8A+4B), stage kh1(t+1), barrier, lgkm0,
// 32 MFMA, barrier}; phase B {read kh1 frags, stage kh0(t+2), barrier, lgkm0,
// 32 MFMA, vmcnt(4|0), barrier}. vmcnt invariant: leftover = kh0(t+2) only.
__global__ __launch_bounds__(512, 2) void k_gemm256(const u16* __restrict__ A,
                                                    const u16* __restrict__ Bm,
                                                    u16* __restrict__ C,
                                                    int M, int N, int K) {
  __shared__ __align__(16) u16 As[2][2][256 * 32];
  __shared__ __align__(16) u16 Bs[2][2][256 * 32];
  const int nbn = N >> 8;
  const int bm = blockIdx.x / nbn, bn = blockIdx.x % nbn;
  const int tid = threadIdx.x;
  const int w = tid >> 6, lane = tid & 63;
  const int wm = w >> 2, wn = w & 3;
  const int lr = lane & 15, lg = lane >> 4;
  const int cw = (lg ^ ((lr >> 1) & 3)) * 8;
  const u16* Ab = A + (size_t)bm * 256 * K;
  const u16* Bb = Bm + (size_t)bn * 256 * K;
  const int NT = K >> 6;

  auto stage = [&](const u16* gb, u16* region, int tile, int kh) {
#pragma unroll
    for (int i = 0; i < 2; i++) {
      int q = tid + i * 512;
      int row = q >> 2, ch = q & 3;
      int sc = ch ^ ((row >> 1) & 3);
      stage16(gb + (size_t)row * K + tile * 64 + kh * 32 + sc * 8, region + q * 8);
    }
  };

  fx4 acc[8][4];
  const fx4 zero4 = {0.f, 0.f, 0.f, 0.f};
#pragma unroll
  for (int m = 0; m < 8; m++)
#pragma unroll
    for (int n = 0; n < 4; n++) acc[m][n] = zero4;

  stage(Ab, &As[0][0][0], 0, 0);
  stage(Bb, &Bs[0][0][0], 0, 0);
  stage(Ab, &As[0][1][0], 0, 1);
  stage(Bb, &Bs[0][1][0], 0, 1);
  stage(Ab, &As[1][0][0], 1, 0);
  stage(Bb, &Bs[1][0][0], 1, 0);
  asm volatile("s_waitcnt vmcnt(4)" ::: "memory");
  __builtin_amdgcn_s_barrier();

  const int arow = (wm * 128 + lr) * 32;
  const int brow = (wn * 64 + lr) * 32;
  bfx8 af[8], bf[4];

#pragma unroll 1
  for (int t = 0; t < NT; t++) {
    const u16* A0 = &As[t & 1][0][0];
    const u16* A1 = &As[t & 1][1][0];
    const u16* B0 = &Bs[t & 1][0][0];
    const u16* B1 = &Bs[t & 1][1][0];
    const int p1 = (t + 1) & 1, p2 = t & 1;

    // ---------- phase A: kh0, all 8 m-frags ----------
#pragma unroll
    for (int mi = 0; mi < 8; mi++) af[mi] = *(const bfx8*)(A0 + arow + mi * 512 + cw);
#pragma unroll
    for (int n = 0; n < 4; n++) bf[n] = *(const bfx8*)(B0 + brow + n * 512 + cw);
    if (t + 1 < NT) {
      stage(Ab, &As[p1][1][0], t + 1, 1);
      stage(Bb, &Bs[p1][1][0], t + 1, 1);
    }
    __builtin_amdgcn_s_barrier();
    asm volatile("s_waitcnt lgkmcnt(0)" ::: "memory");
    __builtin_amdgcn_sched_barrier(0);
    __builtin_amdgcn_s_setprio(1);
#pragma unroll
    for (int mi = 0; mi < 8; mi++)
#pragma unroll
      for (int n = 0; n < 4; n++)
        acc[mi][n] = __builtin_amdgcn_mfma_f32_16x16x32_bf16(af[mi], bf[n], acc[mi][n], 0, 0, 0);
    __builtin_amdgcn_s_setprio(0);
    __builtin_amdgcn_s_barrier();

    // ---------- phase B: kh1, all 8 m-frags ----------
#pragma unroll
    for (int mi = 0; mi < 8; mi++) af[mi] = *(const bfx8*)(A1 + arow + mi * 512 + cw);
#pragma unroll
    for (int n = 0; n < 4; n++) bf[n] = *(const bfx8*)(B1 + brow + n * 512 + cw);
    if (t + 2 < NT) {
      stage(Ab, &As[p2][0][0], t + 2, 0);
      stage(Bb, &Bs[p2][0][0], t + 2, 0);
    }
    __builtin_amdgcn_s_barrier();
    asm volatile("s_waitcnt lgkmcnt(0)" ::: "memory");
    __builtin_amdgcn_sched_barrier(0);
    __builtin_amdgcn_s_setprio(1);
#pragma unroll
    for (int mi = 0; mi < 8; mi++)
#pragma unroll
      for (int n = 0; n < 4; n++)
        acc[mi][n] = __builtin_amdgcn_mfma_f32_16x16x32_bf16(af[mi], bf[n], acc[mi][n], 0, 0, 0);
    __builtin_amdgcn_s_setprio(0);
    if (t + 2 < NT) {
      asm volatile("s_waitcnt vmcnt(4)" ::: "memory");
    } else {
      asm volatile("s_waitcnt vmcnt(0)" ::: "memory");  // tail: no t+2 stages issued
    }
    __builtin_amdgcn_s_barrier();
  }

  const int r0 = bm * 256 + wm * 128, c0 = bn * 256 + wn * 64;
#pragma unroll
  for (int m = 0; m < 8; m++) {
#pragma unroll
    for (int n = 0; n < 4; n++) {
      int c = c0 + n * 16 + lr;
#pragma unroll
      for (int i = 0; i < 4; i++)
        C[(size_t)(r0 + m * 16 + lg * 4 + i) * N + c] = f2bf(acc[m][n][i]);
    }
  }
}

// ======== 128x128 GEMM, 2 merged phases/K-tile, f32+bias out (out-proj) ========
__global__ __launch_bounds__(256, 2) void k_gemmo(const u16* __restrict__ A,
                                                  const u16* __restrict__ Bm,
                                                  float* __restrict__ C,
                                                  const float* __restrict__ bias,
                                                  int M, int N, int K) {
  __shared__ __align__(16) u16 As[2][2][128 * 32];
  __shared__ __align__(16) u16 Bs[2][2][128 * 32];
  const int nbn = N >> 7;
  const int bm = blockIdx.x / nbn, bn = blockIdx.x % nbn;
  const int tid = threadIdx.x;
  const int w = tid >> 6, lane = tid & 63;
  const int wm = w >> 1, wn = w & 1;
  const int lr = lane & 15, lg = lane >> 4;
  const int cw = (lg ^ ((lr >> 1) & 3)) * 8;
  const u16* Ab = A + (size_t)bm * 128 * K;
  const u16* Bb = Bm + (size_t)bn * 128 * K;
  const int NT = K >> 6;

  auto stage = [&](const u16* gb, u16* region, int tile, int kh) {
#pragma unroll
    for (int i = 0; i < 2; i++) {
      int q = tid + i * 256;
      int row = q >> 2, ch = q & 3;
      int sc = ch ^ ((row >> 1) & 3);
      stage16(gb + (size_t)row * K + tile * 64 + kh * 32 + sc * 8, region + q * 8);
    }
  };

  fx4 acc[4][4];
  const fx4 zero4 = {0.f, 0.f, 0.f, 0.f};
#pragma unroll
  for (int m = 0; m < 4; m++)
#pragma unroll
    for (int n = 0; n < 4; n++) acc[m][n] = zero4;

  stage(Ab, &As[0][0][0], 0, 0);
  stage(Bb, &Bs[0][0][0], 0, 0);
  stage(Ab, &As[0][1][0], 0, 1);
  stage(Bb, &Bs[0][1][0], 0, 1);
  stage(Ab, &As[1][0][0], 1, 0);
  stage(Bb, &Bs[1][0][0], 1, 0);
  asm volatile("s_waitcnt vmcnt(4)" ::: "memory");
  __builtin_amdgcn_s_barrier();

  const int arow = (wm * 64 + lr) * 32;
  const int brow = (wn * 64 + lr) * 32;
  bfx8 af[4], bf[4];

#pragma unroll 1
  for (int t = 0; t < NT; t++) {
    const u16* A0 = &As[t & 1][0][0];
    const u16* A1 = &As[t & 1][1][0];
    const u16* B0 = &Bs[t & 1][0][0];
    const u16* B1 = &Bs[t & 1][1][0];
    const int p1 = (t + 1) & 1, p2 = t & 1;

    // phase A: kh0, all 4 m-frags
#pragma unroll
    for (int mi = 0; mi < 4; mi++) af[mi] = *(const bfx8*)(A0 + arow + mi * 512 + cw);
#pragma unroll
    for (int n = 0; n < 4; n++) bf[n] = *(const bfx8*)(B0 + brow + n * 512 + cw);
    if (t + 1 < NT) {
      stage(Ab, &As[p1][1][0], t + 1, 1);
      stage(Bb, &Bs[p1][1][0], t + 1, 1);
    }
    __builtin_amdgcn_s_barrier();
    asm volatile("s_waitcnt lgkmcnt(0)" ::: "memory");
    __builtin_amdgcn_sched_barrier(0);
    __builtin_amdgcn_s_setprio(1);
#pragma unroll
    for (int mi = 0; mi < 4; mi++)
#pragma unroll
      for (int n = 0; n < 4; n++)
        acc[mi][n] = __builtin_amdgcn_mfma_f32_16x16x32_bf16(af[mi], bf[n], acc[mi][n], 0, 0, 0);
    __builtin_amdgcn_s_setprio(0);
    __builtin_amdgcn_s_barrier();

    // phase B: kh1, all 4 m-frags
#pragma unroll
    for (int mi = 0; mi < 4; mi++) af[mi] = *(const bfx8*)(A1 + arow + mi * 512 + cw);
#pragma unroll
    for (int n = 0; n < 4; n++) bf[n] = *(const bfx8*)(B1 + brow + n * 512 + cw);
    if (t + 2 < NT) {
      stage(Ab, &As[p2][0][0], t + 2, 0);
      stage(Bb, &Bs[p2][0][0], t + 2, 0);
    }
    __builtin_amdgcn_s_barrier();
    asm volatile("s_waitcnt lgkmcnt(0)" ::: "memory");
    __builtin_amdgcn_sched_barrier(0);
    __builtin_amdgcn_s_setprio(1);
#pragma unroll
    for (int mi = 0; mi < 4; mi++)
#pragma unroll
      for (int n = 0; n < 4; n++)
        acc[mi][n] = __builtin_amdgcn_mfma_f32_16x16x32_bf16(af[mi], bf[n], acc[mi][n], 0, 0, 0);
    __builtin_amdgcn_s_setprio(0);
    if (t + 2 < NT) {
      asm volatile("s_waitcnt vmcnt(4)" ::: "memory");
    } else {
      asm volatile("s_waitcnt vmcnt(0)" ::: "memory");  // tail drain (race fix)
    }
    __builtin_amdgcn_s_barrier();
  }

  const int r0 = bm * 128 + wm * 64, c0 = bn * 128 + wn * 64;
#pragma unroll
  for (int m = 0; m < 4; m++) {
#pragma unroll
    for (int n = 0; n < 4; n++) {
      int c = c0 + n * 16 + lr;
#pragma unroll
      for (int i = 0; i < 4; i++)
        C[(size_t)(r0 + m * 16 + lg * 4 + i) * N + c] = acc[m][n][i] + bias[c];
    }
  }
}

// ---------------- Q/K epilogue: rmsnorm + rope, relayout ----------------
__global__ __launch_bounds__(256) void k_qkpost(const u16* __restrict__ qkv,
                                                const float* __restrict__ cosp,
                                                const float* __restrict__ sinp,
                                                const float* __restrict__ gq,
                                                const float* __restrict__ gk,
                                                u16* __restrict__ Qo,
                                                u16* __restrict__ Ko) {
  int bi = blockIdx.x;
  int hh = bi % 24;
  int t64 = (bi / 24) % 32;
  int b = bi / 768;
  int tid = threadIdx.x;
  int j = tid >> 2, p = tid & 3;
  int t = t64 * 64 + j;
  bool isq = hh < 16;
  int colbase = isq ? hh * 128 : 2048 + (hh - 16) * 128;
  const u16* src = qkv + ((size_t)(b * T_ + t)) * NQKV + colbase + p * 32;

  float xv[32];
#pragma unroll
  for (int c = 0; c < 4; c++) {
    uint4 raw = *(const uint4*)(src + c * 8);
    u32 wd[4] = {raw.x, raw.y, raw.z, raw.w};
#pragma unroll
    for (int q2 = 0; q2 < 4; q2++) {
      xv[c * 8 + q2 * 2 + 0] = __uint_as_float(wd[q2] << 16);
      xv[c * 8 + q2 * 2 + 1] = __uint_as_float(wd[q2] & 0xffff0000u);
    }
  }
  float ss = 0.f;
#pragma unroll
  for (int i = 0; i < 32; i++) ss += xv[i] * xv[i];
  ss += __shfl_xor(ss, 1);
  ss += __shfl_xor(ss, 2);
  float rinv = rsqrtf(ss * (1.0f / 128.0f) + 1e-6f);
  const float* g = isq ? gq : gk;
  const float* cr = cosp + (size_t)t * 128 + p * 32;
  const float* sr = sinp + (size_t)t * 128 + p * 32;

  float ov[32];
#pragma unroll
  for (int i = 0; i < 32; i++) {
    float y = xv[i] * rinv * g[p * 32 + i];
    float oth = __shfl_xor(y, 2);
    float rot = (p < 2) ? -oth : oth;
    ov[i] = y * cr[i] + rot * sr[i];
  }

  uint4 pk[4];
#pragma unroll
  for (int c = 0; c < 4; c++) {
    u32 wd[4];
#pragma unroll
    for (int q2 = 0; q2 < 4; q2++)
      wd[q2] = (u32)f2bf(ov[c * 8 + q2 * 2]) | ((u32)f2bf(ov[c * 8 + q2 * 2 + 1]) << 16);
    pk[c] = make_uint4(wd[0], wd[1], wd[2], wd[3]);
  }

  if (isq) {
    u16* dst = Qo + (((size_t)(b * NH + hh)) * T_ + t) * HD + p * 32;
#pragma unroll
    for (int c = 0; c < 4; c++) *(uint4*)(dst + c * 8) = pk[c];
  } else {
    int hk = hh - 16;
    u16* dstrow = Ko + (((size_t)(b * NKV + hk)) * T_ + t) * HD;
#pragma unroll
    for (int c = 0; c < 4; c++) {
      int C = p * 4 + c;
      int Cs = C ^ (t & 7);  // XOR swizzle (16 chunks/row), matches attn read
      *(uint4*)(dstrow + Cs * 8) = pk[c];
    }
  }
}

// ---------------- V transpose: qkv[...,3072+] -> vt[b][hkv][d][t] ----------------
__global__ __launch_bounds__(256) void k_vtr(const u16* __restrict__ qkv,
                                             u16* __restrict__ vt) {
  __shared__ __align__(16) u16 sm[128 * 64];
  int bi = blockIdx.x;
  int hv = bi & 7;
  int t64 = (bi >> 3) & 31;
  int b = bi >> 8;
  int tid = threadIdx.x;
#pragma unroll
  for (int it = 0; it < 4; it++) {
    int idx = tid + it * 256;
    int tok = idx >> 4, c = idx & 15;
    uint4 raw = *(const uint4*)(qkv + ((size_t)(b * T_ + t64 * 64 + tok)) * NQKV +
                                3072 + hv * 128 + c * 8);
    u32 wd[4] = {raw.x, raw.y, raw.z, raw.w};
#pragma unroll
    for (int q2 = 0; q2 < 4; q2++) {
      sm[(c * 8 + q2 * 2 + 0) * 64 + tok] = (u16)(wd[q2] & 0xffffu);
      sm[(c * 8 + q2 * 2 + 1) * 64 + tok] = (u16)(wd[q2] >> 16);
    }
  }
  __syncthreads();
  int d = tid >> 1, half = tid & 1;
  size_t rowb = (((size_t)(b * NKV + hv)) * HD + d) * T_ + t64 * 64;
#pragma unroll
  for (int c = 0; c < 4; c++) {
    int cg = half * 4 + c;
    int cs = cg ^ (d & 7);
    u32 wd[4];
#pragma unroll
    for (int q2 = 0; q2 < 4; q2++) {
      u32 lo = sm[d * 64 + half * 32 + c * 8 + 2 * q2];
      u32 hi = sm[d * 64 + half * 32 + c * 8 + 2 * q2 + 1];
      wd[q2] = lo | (hi << 16);
    }
    *(uint4*)(vt + rowb + cs * 8) = make_uint4(wd[0], wd[1], wd[2], wd[3]);
  }
}

// ---------------- flash attention v5 (r11, PASSING ~72us): transposed-S + cvt_pk ----
__global__ __launch_bounds__(512, 4) void k_attn(const u16* __restrict__ Qg,
                                                 const u16* __restrict__ Kg,
                                                 const u16* __restrict__ Vg,
                                                 u16* __restrict__ Og) {
  __shared__ __align__(16) u16 Ks[2][64 * 128];
  __shared__ __align__(16) u16 Vs[2][128 * 64];
  __shared__ __align__(16) u16 Ps[8][16 * 64];
  const int bi = blockIdx.x;
  const int zr = bi & 15, h = (bi >> 4) & 15, b = bi >> 8;
  const int z = b ? (15 - zr) : zr;
  const int hkv = h >> 1;
  const int tid = threadIdx.x, w = tid >> 6, lane = tid & 63;
  const int lr = lane & 15, lg = lane >> 4;
  const int zt = (w < 4) ? z : (31 - z);
  const int qr0 = zt * 64 + (w & 3) * 16;
  const int qrow = qr0 + lr;
  const int nch = 32 - z;
  const int myl = zt + 1;

  const u16* kb = Kg + ((size_t)(b * NKV + hkv)) * T_ * HD;
  const u16* vb = Vg + ((size_t)(b * NKV + hkv)) * HD * T_;
  u16* pw = &Ps[w][0];
  const fx4 zero4 = {0.f, 0.f, 0.f, 0.f};

  auto stageKV = [&](int buf, int kv0) {
    u16* Kd = &Ks[buf][0];
    u16* Vd = &Vs[buf][0];
#pragma unroll
    for (int it = 0; it < 2; it++) {
      int r = it * 32 + (tid >> 4);
      stage16(kb + (size_t)(kv0 + r) * HD + (tid & 15) * 8, Kd + it * 4096 + tid * 8);
      int d = it * 64 + (tid >> 3);
      stage16(vb + (size_t)d * T_ + kv0 + (tid & 7) * 8, Vd + it * 4096 + tid * 8);
    }
  };

  const u16* qbase = Qg + (((size_t)(b * NH + h)) * T_ + qrow) * HD;
  bfx8 qf[4];
#pragma unroll
  for (int kk = 0; kk < 4; kk++) qf[kk] = *(const bfx8*)(qbase + kk * 32 + lg * 8);

  fx4 o[8];
#pragma unroll
  for (int nf = 0; nf < 8; nf++) o[nf] = zero4;
  float l_i = 0.f;

  stageKV(0, 0);
  asm volatile("s_waitcnt vmcnt(0)" ::: "memory");
  __builtin_amdgcn_s_barrier();
  int cur = 0;

#pragma unroll 1
  for (int ch = 0; ch < nch; ch++) {
    if (ch + 1 < nch) {
      stageKV(cur ^ 1, (ch + 1) * 64);
      asm volatile("s_waitcnt vmcnt(4)" ::: "memory");
    } else {
      asm volatile("s_waitcnt vmcnt(0)" ::: "memory");
    }
    __builtin_amdgcn_s_barrier();

    if (ch < myl) {
      const u16* Kd = &Ks[cur][0];
      const u16* Vd = &Vs[cur][0];
      const int kv0 = ch * 64;
      const bool diag = (ch == zt);

      // ---- S^T = mfma(K, Q): lane holds kv = n*16 + 4*lg + i, col q = lr ----
      fx4 sa[4];
#pragma unroll
      for (int n = 0; n < 4; n++) sa[n] = zero4;
      __builtin_amdgcn_s_setprio(1);
#pragma unroll
      for (int n = 0; n < 4; n++) {
        const int kvl = n * 16 + lr;
        const u16* krow = Kd + kvl * 128;
#pragma unroll
        for (int kk = 0; kk < 4; kk++) {
          int cs = (kk * 4 + lg) ^ (kvl & 7);
          bfx8 kf = *(const bfx8*)(krow + cs * 8);
          sa[n] = __builtin_amdgcn_mfma_f32_16x16x32_bf16(kf, qf[kk], sa[n], 0, 0, 0);
        }
      }
      __builtin_amdgcn_s_setprio(0);

      // ---- no-max softmax + packed P-store (4 consecutive kv per lane) ----
#pragma unroll
      for (int n = 0; n < 4; n++) {
        float p0 = exp2f(sa[n][0] * SC2_);
        float p1 = exp2f(sa[n][1] * SC2_);
        float p2 = exp2f(sa[n][2] * SC2_);
        float p3 = exp2f(sa[n][3] * SC2_);
        if (diag) {
          int kvg = kv0 + n * 16 + 4 * lg;
          p0 = (kvg + 0 > qrow) ? 0.f : p0;
          p1 = (kvg + 1 > qrow) ? 0.f : p1;
          p2 = (kvg + 2 > qrow) ? 0.f : p2;
          p3 = (kvg + 3 > qrow) ? 0.f : p3;
        }
        l_i += (p0 + p1) + (p2 + p3);
        u32 w0 = cvtpk(p0, p1);
        u32 w1 = cvtpk(p2, p3);
        int c = 2 * n + (lg >> 1);
        int cs = c ^ (lr & 7);
        *(uint2*)(pw + lr * 64 + cs * 8 + 4 * (lg & 1)) = make_uint2(w0, w1);
      }
      asm volatile("s_waitcnt lgkmcnt(0)" ::: "memory");
      __builtin_amdgcn_sched_barrier(0);

      // ---- O += P V ----
      bfx8 pa[2];
#pragma unroll
      for (int ks = 0; ks < 2; ks++) {
        int cp = (4 * ks + lg) ^ (lr & 7);
        pa[ks] = *(const bfx8*)(pw + lr * 64 + cp * 8);
      }
      __builtin_amdgcn_s_setprio(1);
#pragma unroll
      for (int nf = 0; nf < 8; nf++) {
        int d = nf * 16 + lr;
        const u16* vrow = Vd + d * 64;
#pragma unroll
        for (int ks = 0; ks < 2; ks++) {
          int cv = (4 * ks + lg) ^ (d & 7);
          bfx8 vf = *(const bfx8*)(vrow + cv * 8);
          o[nf] = __builtin_amdgcn_mfma_f32_16x16x32_bf16(pa[ks], vf, o[nf], 0, 0, 0);
        }
      }
      __builtin_amdgcn_s_setprio(0);
    }
    __builtin_amdgcn_s_barrier();
    cur ^= 1;
  }

  float lt = l_i + __shfl_xor(l_i, 16);
  lt += __shfl_xor(lt, 32);
  float inv[4];
#pragma unroll
  for (int i = 0; i < 4; i++) inv[i] = 1.0f / __shfl(lt, 4 * lg + i);
  u16* ob = Og + ((size_t)(b * T_ + qr0)) * DM + h * HD;
#pragma unroll
  for (int nf = 0; nf < 8; nf++)
#pragma unroll
    for (int i = 0; i < 4; i++)
      ob[(size_t)(4 * lg + i) * DM + nf * 16 + lr] = f2bf(o[nf][i] * inv[i]);
}

// ---------------- launch ----------------
extern "C" void kernel_launch(void* const* d_in, const int* in_sizes, int n_in,
                              void* d_out, int out_size, void* d_ws, size_t ws_size,
                              hipStream_t stream) {
  const float* x = (const float*)d_in[0];
  const float* cosp = (const float*)d_in[2];
  const float* sinp = (const float*)d_in[3];
  const float* Wq = (const float*)d_in[4];
  const float* Wk = (const float*)d_in[5];
  const float* Wv = (const float*)d_in[6];
  const float* Wo = (const float*)d_in[7];
  const float* bo = (const float*)d_in[8];
  const float* gq = (const float*)d_in[9];
  const float* gk = (const float*)d_in[10];

  char* ws = (char*)d_ws;
  u16* xbf  = (u16*)(ws + 0);           // 16 MB
  u16* wqkv = (u16*)(ws + 16777216);    // 16 MB (contiguous with wo below)
  u16* wo   = (u16*)(ws + 33554432);    // 8 MB
  u16* qkv  = (u16*)(ws + 41943040);    // 32 MB
  u16* qb   = (u16*)(ws + 75497472);    // 16 MB
  u16* kb   = (u16*)(ws + 92274688);    // 8 MB
  u16* vt   = (u16*)(ws + 100663296);   // 8 MB
  u16* ab   = (u16*)(ws + 109051904);   // 16 MB
  float* out = (float*)d_out;

  k_cvt<<<8192, 256, 0, stream>>>(x, xbf, 8388608);
  k_cvtw<<<12288, 256, 0, stream>>>(Wq, Wk, Wv, Wo, wqkv);  // wqkv|wo contiguous

  k_gemm256<<<256, 512, 0, stream>>>(xbf, wqkv, qkv, 4096, 4096, 2048);
  k_qkpost<<<1536, 256, 0, stream>>>(qkv, cosp, sinp, gq, gk, qb, kb);
  k_vtr<<<512, 256, 0, stream>>>(qkv, vt);
  k_attn<<<512, 512, 0, stream>>>(qb, kb, vt, ab);
  k_gemmo<<<512, 256, 0, stream>>>(ab, wo, out, bo, 4096, 2048, 2048);
}